// Round 3
// baseline (351.468 us; speedup 1.0000x reference)
//
#include <hip/hip_runtime.h>
#include <hip/hip_bf16.h>

#define OUT_F 4096
#define IN_F 4096
#define MROWS 2048            // 4*512 batch rows
#define FFT_N 4096

typedef short bf16x8 __attribute__((ext_vector_type(8)));
typedef float f32x4 __attribute__((ext_vector_type(4)));

// ================= bucket build (counting sort by column v) =================
__global__ void hist_kernel(const int* __restrict__ idx, unsigned* __restrict__ cnt, int nnz) {
    int k = blockIdx.x * blockDim.x + threadIdx.x;
    if (k < nnz) atomicAdd(&cnt[idx[k] & (IN_F - 1)], 1u);
}

__global__ void __launch_bounds__(256) scan_kernel(const unsigned* __restrict__ cnt,
                                                   unsigned* __restrict__ start,
                                                   unsigned* __restrict__ pos) {
    __shared__ unsigned part[257];
    const int t = threadIdx.x;
    unsigned s = 0;
    #pragma unroll
    for (int j = 0; j < 16; ++j) s += cnt[t * 16 + j];
    part[t + 1] = s;
    if (t == 0) part[0] = 0;
    __syncthreads();
    if (t == 0)
        for (int i = 1; i <= 256; ++i) part[i] += part[i - 1];
    __syncthreads();
    unsigned run = part[t];
    #pragma unroll
    for (int j = 0; j < 16; ++j) {
        start[t * 16 + j] = run;
        pos[t * 16 + j] = run;
        run += cnt[t * 16 + j];
    }
    if (t == 255) start[4096] = run;
}

__global__ void bucket_scatter_kernel(const int* __restrict__ idx, const float* __restrict__ re,
                                      const float* __restrict__ im, unsigned* __restrict__ pos,
                                      unsigned* __restrict__ packed, float2* __restrict__ val,
                                      int nnz) {
    int k = blockIdx.x * blockDim.x + threadIdx.x;
    if (k < nnz) {
        int id = idx[k];
        unsigned v = (unsigned)id & (IN_F - 1);
        unsigned u = (unsigned)id >> 12;
        unsigned p = atomicAdd(&pos[v], 1u);
        packed[p] = ((unsigned)k << 12) | u;   // k in high 20 bits -> max(packed) == max(k)
        val[p] = make_float2(re[k], im[k]);
    }
}

// ================= 16-pt inverse FFT building blocks =================
__device__ __forceinline__ void bflyw(float2& a, float2& b, float wr, float wi) {
    float tr = b.x * wr - b.y * wi;
    float ti = b.x * wi + b.y * wr;
    b.x = a.x - tr; b.y = a.y - ti;
    a.x += tr; a.y += ti;
}
__device__ __forceinline__ void bfly1(float2& a, float2& b) {   // w = 1
    float tr = b.x, ti = b.y;
    b.x = a.x - tr; b.y = a.y - ti;
    a.x += tr; a.y += ti;
}
__device__ __forceinline__ void bflyI(float2& a, float2& b) {   // w = +i
    float tr = -b.y, ti = b.x;
    b.x = a.x - tr; b.y = a.y - ti;
    a.x += tr; a.y += ti;
}

#define C8f  0.70710678118654752f
#define C16f 0.92387953251128676f
#define S16f 0.38268343236508977f

// inverse 16-pt FFT (+i convention). Input in bit-reversed slots, output natural.
__device__ __forceinline__ void fft16(float2 r[16]) {
    bfly1(r[0], r[1]);  bfly1(r[2], r[3]);  bfly1(r[4], r[5]);   bfly1(r[6], r[7]);
    bfly1(r[8], r[9]);  bfly1(r[10], r[11]); bfly1(r[12], r[13]); bfly1(r[14], r[15]);
    bfly1(r[0], r[2]);  bflyI(r[1], r[3]);
    bfly1(r[4], r[6]);  bflyI(r[5], r[7]);
    bfly1(r[8], r[10]); bflyI(r[9], r[11]);
    bfly1(r[12], r[14]); bflyI(r[13], r[15]);
    bfly1(r[0], r[4]);  bflyw(r[1], r[5], C8f, C8f);  bflyI(r[2], r[6]);  bflyw(r[3], r[7], -C8f, C8f);
    bfly1(r[8], r[12]); bflyw(r[9], r[13], C8f, C8f); bflyI(r[10], r[14]); bflyw(r[11], r[15], -C8f, C8f);
    bfly1(r[0], r[8]);
    bflyw(r[1], r[9],  C16f, S16f);
    bflyw(r[2], r[10], C8f,  C8f);
    bflyw(r[3], r[11], S16f, C16f);
    bflyI(r[4], r[12]);
    bflyw(r[5], r[13], -S16f, C16f);
    bflyw(r[6], r[14], -C8f,  C8f);
    bflyw(r[7], r[15], -C16f, S16f);
}

// LDS XOR swizzle: bijective on [0,4096)
__device__ __forceinline__ int swz(int a) { return a ^ ((a >> 5) & 31); }

__device__ __forceinline__ void fft4096_lds(float* bre, float* bim, int t, float2 r[16],
                                            const int* rv) {
    // ---- phase 1: 16-pt over n1, column n2 = t ----
    #pragma unroll
    for (int n1 = 0; n1 < 16; ++n1) {
        int a = swz(256 * n1 + t);
        r[rv[n1]] = make_float2(bre[a], bim[a]);
    }
    fft16(r);
    {
        float s, c;
        sincosf((float)t * 1.5339807878856412e-3f, &s, &c);   // 2*pi/4096
        float2 w = make_float2(c, s), cur = make_float2(1.f, 0.f);
        #pragma unroll
        for (int k = 0; k < 16; ++k) {
            float xr = r[k].x * cur.x - r[k].y * cur.y;
            float xi = r[k].x * cur.y + r[k].y * cur.x;
            r[k].x = xr; r[k].y = xi;
            float nr = cur.x * w.x - cur.y * w.y;
            float ni = cur.x * w.y + cur.y * w.x;
            cur.x = nr; cur.y = ni;
        }
    }
    #pragma unroll
    for (int k = 0; k < 16; ++k) {
        int a = swz(256 * k + t);
        bre[a] = r[k].x; bim[a] = r[k].y;
    }
    __syncthreads();

    // ---- phase 2 ----
    const int k1 = t >> 4;
    const int lo = t & 15;
    const int base2 = 256 * k1 + lo;
    #pragma unroll
    for (int m1 = 0; m1 < 16; ++m1) {
        int a = swz(base2 + 16 * m1);
        r[rv[m1]] = make_float2(bre[a], bim[a]);
    }
    fft16(r);
    {
        float s, c;
        sincosf((float)lo * 2.45436926061702596e-2f, &s, &c); // 2*pi/256
        float2 w = make_float2(c, s), cur = make_float2(1.f, 0.f);
        #pragma unroll
        for (int k = 0; k < 16; ++k) {
            float xr = r[k].x * cur.x - r[k].y * cur.y;
            float xi = r[k].x * cur.y + r[k].y * cur.x;
            r[k].x = xr; r[k].y = xi;
            float nr = cur.x * w.x - cur.y * w.y;
            float ni = cur.x * w.y + cur.y * w.x;
            cur.x = nr; cur.y = ni;
        }
    }
    #pragma unroll
    for (int k = 0; k < 16; ++k) {
        int a = swz(base2 + 16 * k);
        bre[a] = r[k].x; bim[a] = r[k].y;
    }
    __syncthreads();

    // ---- phase 3 ----
    const int base3 = 256 * k1 + 16 * lo;
    #pragma unroll
    for (int m = 0; m < 16; ++m) {
        int a = swz(base3 + m);
        r[rv[m]] = make_float2(bre[a], bim[a]);
    }
    fft16(r);
    __syncthreads();   // all reads done before digit-swap scatter overwrites
}

// ---------------- pass 1: bucket-scatter into LDS + 4096-pt IFFT, complex out ----------------
__global__ void __launch_bounds__(256) ifft_pass1_kernel(const unsigned* __restrict__ start,
                                                         const unsigned* __restrict__ packed,
                                                         const float2* __restrict__ val,
                                                         float2* __restrict__ outp) {
    __shared__ float bre[FFT_N];
    __shared__ float bim[FFT_N];
    __shared__ unsigned kwin[FFT_N];
    const int t = threadIdx.x;
    const int v = blockIdx.x;

    for (int j = t; j < FFT_N; j += 256) { bre[j] = 0.f; bim[j] = 0.f; kwin[j] = 0u; }
    __syncthreads();

    const unsigned s0 = start[v], s1 = start[v + 1];
    for (unsigned i = s0 + t; i < s1; i += 256)
        atomicMax(&kwin[packed[i] & 4095u], packed[i]);
    __syncthreads();
    for (unsigned i = s0 + t; i < s1; i += 256) {
        unsigned pk = packed[i];
        unsigned u = pk & 4095u;
        if (kwin[u] == pk) {
            float2 w = val[i];
            int a = swz((int)u);
            bre[a] = w.x; bim[a] = w.y;
        }
    }
    __syncthreads();

    const int rv[16] = {0, 8, 4, 12, 2, 10, 6, 14, 1, 9, 5, 13, 3, 11, 7, 15};
    float2 r[16];
    fft4096_lds(bre, bim, t, r, rv);

    const float scale = 1.0f / 4096.0f;
    const int k1 = t >> 4, lo = t & 15;
    const int outb = k1 + 16 * lo;
    #pragma unroll
    for (int j2 = 0; j2 < 16; ++j2) {
        int a = swz(outb + 256 * j2);
        bre[a] = r[j2].x * scale;
        bim[a] = r[j2].y * scale;
    }
    __syncthreads();

    float2* __restrict__ og = outp + (size_t)v * FFT_N;
    for (int j = t; j < FFT_N; j += 256) {
        int a = swz(j);
        og[j] = make_float2(bre[a], bim[a]);
    }
}

// ---------------- pass 2: 4096-pt IFFT per row, real part -> bf16 ----------------
__global__ void __launch_bounds__(256) ifft_pass2_kernel(const float2* __restrict__ data,
                                                         __hip_bfloat16* __restrict__ wout) {
    __shared__ float bre[FFT_N];
    __shared__ float bim[FFT_N];
    const int t = threadIdx.x;
    const size_t rowoff = (size_t)blockIdx.x * FFT_N;
    const float2* __restrict__ g = data + rowoff;

    for (int j = t; j < FFT_N; j += 256) {
        float2 v = g[j];
        int a = swz(j);
        bre[a] = v.x; bim[a] = v.y;
    }
    __syncthreads();

    const int rv[16] = {0, 8, 4, 12, 2, 10, 6, 14, 1, 9, 5, 13, 3, 11, 7, 15};
    float2 r[16];
    fft4096_lds(bre, bim, t, r, rv);

    const float scale = 1.0f / 4096.0f;
    const int k1 = t >> 4, lo = t & 15;
    const int outb = k1 + 16 * lo;
    #pragma unroll
    for (int j2 = 0; j2 < 16; ++j2) {
        int a = swz(outb + 256 * j2);
        bre[a] = r[j2].x * scale;
    }
    __syncthreads();

    __hip_bfloat16* __restrict__ o = wout + rowoff;
    for (int j = t; j < FFT_N; j += 256) o[j] = __float2bfloat16(bre[swz(j)]);
}

// ---------------- in-place complex transpose (4096x4096 float2) ----------------
__global__ void transpose_kernel(float2* __restrict__ A) {
    const int bi = blockIdx.y, bj = blockIdx.x;
    if (bi > bj) return;
    __shared__ float2 tA[32][33];
    __shared__ float2 tB[32][33];
    const int tx = threadIdx.x;   // 0..31
    const int ty = threadIdx.y;   // 0..7
    #pragma unroll
    for (int k = 0; k < 4; ++k) {
        int r = ty + k * 8;
        tA[r][tx] = A[(size_t)(bi * 32 + r) * IN_F + bj * 32 + tx];
    }
    if (bi != bj) {
        #pragma unroll
        for (int k = 0; k < 4; ++k) {
            int r = ty + k * 8;
            tB[r][tx] = A[(size_t)(bj * 32 + r) * IN_F + bi * 32 + tx];
        }
    }
    __syncthreads();
    #pragma unroll
    for (int k = 0; k < 4; ++k) {
        int r = ty + k * 8;
        A[(size_t)(bj * 32 + r) * IN_F + bi * 32 + tx] = tA[tx][r];
    }
    if (bi != bj) {
        #pragma unroll
        for (int k = 0; k < 4; ++k) {
            int r = ty + k * 8;
            A[(size_t)(bi * 32 + r) * IN_F + bj * 32 + tx] = tB[tx][r];
        }
    }
}

// ---------------- f32 -> bf16 cast of x ----------------
__global__ void cast_x_kernel(const float4* __restrict__ x, ushort4* __restrict__ xb, int n4) {
    int i = blockIdx.x * blockDim.x + threadIdx.x;
    if (i < n4) {
        float4 v = x[i];
        __hip_bfloat16 a = __float2bfloat16(v.x);
        __hip_bfloat16 b = __float2bfloat16(v.y);
        __hip_bfloat16 c = __float2bfloat16(v.z);
        __hip_bfloat16 d = __float2bfloat16(v.w);
        ushort4 o;
        o.x = *reinterpret_cast<unsigned short*>(&a);
        o.y = *reinterpret_cast<unsigned short*>(&b);
        o.z = *reinterpret_cast<unsigned short*>(&c);
        o.w = *reinterpret_cast<unsigned short*>(&d);
        xb[i] = o;
    }
}

// ---------------- bf16 MFMA GEMM: out[M,N] = X[M,K] * W[N,K]^T + bias ----------------
__global__ void __launch_bounds__(256) gemm_kernel(const __hip_bfloat16* __restrict__ X,
                                                   const __hip_bfloat16* __restrict__ W,
                                                   const float* __restrict__ bias,
                                                   float* __restrict__ out) {
    __shared__ __align__(16) __hip_bfloat16 sA[128 * 32];   // 8 KB
    __shared__ __align__(16) __hip_bfloat16 sB[128 * 32];   // 8 KB
    const int tid = threadIdx.x;
    const int wv = tid >> 6;        // wave 0..3
    const int ln = tid & 63;
    // XCD-aware swizzle: 512 blocks, 8 XCDs, 64 per chunk (bijective: 512%8==0)
    const int bid = blockIdx.x;
    const int sw = ((bid & 7) << 6) | (bid >> 3);
    const int n0 = (sw & 31) * 128;   // 32 n-tiles
    const int m0 = (sw >> 5) * 128;   // 16 m-tiles
    const int wm = wv >> 1, wn = wv & 1;
    const int r16 = ln & 15, kg = ln >> 4;

    f32x4 acc[4][4];
    #pragma unroll
    for (int i = 0; i < 4; ++i)
        #pragma unroll
        for (int j = 0; j < 4; ++j) acc[i][j] = (f32x4){0.f, 0.f, 0.f, 0.f};

    for (int k0 = 0; k0 < IN_F; k0 += 32) {
        __syncthreads();
        #pragma unroll
        for (int c = 0; c < 2; ++c) {
            const int fc = (c * 4 + wv) * 64 + ln;   // chunk index 0..511
            const int row = fc >> 2;
            const int cc = fc & 3;
            const __hip_bfloat16* ga = X + (size_t)(m0 + row) * IN_F + k0 + cc * 8;
            __builtin_amdgcn_global_load_lds(
                (const __attribute__((address_space(1))) void*)ga,
                (__attribute__((address_space(3))) void*)(sA + (size_t)(c * 4 + wv) * 512),
                16, 0, 0);
            const __hip_bfloat16* gb = W + (size_t)(n0 + row) * IN_F + k0 + cc * 8;
            __builtin_amdgcn_global_load_lds(
                (const __attribute__((address_space(1))) void*)gb,
                (__attribute__((address_space(3))) void*)(sB + (size_t)(c * 4 + wv) * 512),
                16, 0, 0);
        }
        __syncthreads();

        bf16x8 af[4], bfr[4];
        #pragma unroll
        for (int i = 0; i < 4; ++i)
            af[i] = *reinterpret_cast<const bf16x8*>(&sA[(wm * 64 + i * 16 + r16) * 32 + kg * 8]);
        #pragma unroll
        for (int j = 0; j < 4; ++j)
            bfr[j] = *reinterpret_cast<const bf16x8*>(&sB[(wn * 64 + j * 16 + r16) * 32 + kg * 8]);
        #pragma unroll
        for (int i = 0; i < 4; ++i)
            #pragma unroll
            for (int j = 0; j < 4; ++j)
                acc[i][j] = __builtin_amdgcn_mfma_f32_16x16x32_bf16(af[i], bfr[j], acc[i][j], 0, 0, 0);
    }

    // epilogue: D[m][n], n = lane&15, m = (lane>>4)*4 + e
    #pragma unroll
    for (int i = 0; i < 4; ++i)
        #pragma unroll
        for (int j = 0; j < 4; ++j) {
            const int n = n0 + wn * 64 + j * 16 + r16;
            const float bs = bias[n];
            #pragma unroll
            for (int e = 0; e < 4; ++e) {
                const int m = m0 + wm * 64 + i * 16 + kg * 4 + e;
                out[(size_t)m * OUT_F + n] = acc[i][j][e] + bs;
            }
        }
}

extern "C" void kernel_launch(void* const* d_in, const int* in_sizes, int n_in,
                              void* d_out, int out_size, void* d_ws, size_t ws_size,
                              hipStream_t stream) {
    const float* x    = (const float*)d_in[0];
    const float* sre  = (const float*)d_in[1];
    const float* sim  = (const float*)d_in[2];
    const int*   sidx = (const int*)d_in[3];
    const float* bias = (const float*)d_in[4];
    const int nnz = in_sizes[1];
    float* out = (float*)d_out;

    char* ws = (char*)d_ws;
    // A (spectrum, complex, in-place FFT/transpose): 128 MiB @ 0
    float2* A = (float2*)ws;
    // bucket arrays alias the Wb region (dead before pass 2 writes Wb)
    unsigned* packed = (unsigned*)(ws + 134217728);                       // 4*nnz
    float2* bval = (float2*)(ws + 134217728 + 4194304);                   // 8*nnz
    __hip_bfloat16* Wb = (__hip_bfloat16*)(ws + 134217728);               // 33.5 MB (pass2 out)
    __hip_bfloat16* Xb = (__hip_bfloat16*)(ws + 134217728 + 33554432);    // 16.8 MB
    char* ctl = ws + 134217728 + 33554432 + 16777216;
    unsigned* cnt   = (unsigned*)(ctl);            // 4096
    unsigned* start = (unsigned*)(ctl + 32768);    // 4097
    unsigned* pos   = (unsigned*)(ctl + 65536);    // 4096

    hipMemsetAsync(cnt, 0, 4096 * sizeof(unsigned), stream);

    const int sb = (nnz + 255) / 256;
    hist_kernel<<<sb, 256, 0, stream>>>(sidx, cnt, nnz);
    scan_kernel<<<1, 256, 0, stream>>>(cnt, start, pos);
    bucket_scatter_kernel<<<sb, 256, 0, stream>>>(sidx, sre, sim, pos, packed, bval, nnz);

    // pass 1: scatter winners into LDS + ifft along original axis 0, rows = columns v
    ifft_pass1_kernel<<<FFT_N, 256, 0, stream>>>(start, packed, bval, A);
    // transpose so pass 2 is also row-wise
    transpose_kernel<<<dim3(128, 128), dim3(32, 8), 0, stream>>>(A);
    // pass 2: ifft along axis 1, real part -> bf16 weight [OUT_F][IN_F]
    ifft_pass2_kernel<<<FFT_N, 256, 0, stream>>>(A, Wb);

    cast_x_kernel<<<(MROWS * IN_F / 4 + 255) / 256, 256, 0, stream>>>(
        (const float4*)x, (ushort4*)Xb, MROWS * IN_F / 4);

    gemm_kernel<<<512, 256, 0, stream>>>(Xb, Wb, bias, out);
}

// Round 4
// 345.706 us; speedup vs baseline: 1.0167x; 1.0167x over previous
//
#include <hip/hip_runtime.h>
#include <hip/hip_bf16.h>

#define OUT_F 4096
#define IN_F 4096
#define MROWS 2048            // 4*512 batch rows
#define FFT_N 4096

typedef short bf16x8 __attribute__((ext_vector_type(8)));
typedef float f32x4 __attribute__((ext_vector_type(4)));

// ================= bucket build (counting sort by column v) =================
__global__ void hist_kernel(const int* __restrict__ idx, unsigned* __restrict__ cnt, int nnz) {
    int k = blockIdx.x * blockDim.x + threadIdx.x;
    if (k < nnz) atomicAdd(&cnt[idx[k] & (IN_F - 1)], 1u);
}

__global__ void __launch_bounds__(256) scan_kernel(const unsigned* __restrict__ cnt,
                                                   unsigned* __restrict__ start,
                                                   unsigned* __restrict__ pos) {
    __shared__ unsigned part[257];
    const int t = threadIdx.x;
    unsigned s = 0;
    #pragma unroll
    for (int j = 0; j < 16; ++j) s += cnt[t * 16 + j];
    part[t + 1] = s;
    if (t == 0) part[0] = 0;
    __syncthreads();
    if (t == 0)
        for (int i = 1; i <= 256; ++i) part[i] += part[i - 1];
    __syncthreads();
    unsigned run = part[t];
    #pragma unroll
    for (int j = 0; j < 16; ++j) {
        start[t * 16 + j] = run;
        pos[t * 16 + j] = run;
        run += cnt[t * 16 + j];
    }
    if (t == 255) start[4096] = run;
}

__global__ void bucket_scatter_kernel(const int* __restrict__ idx, const float* __restrict__ re,
                                      const float* __restrict__ im, unsigned* __restrict__ pos,
                                      unsigned* __restrict__ packed, float2* __restrict__ val,
                                      int nnz) {
    int k = blockIdx.x * blockDim.x + threadIdx.x;
    if (k < nnz) {
        int id = idx[k];
        unsigned v = (unsigned)id & (IN_F - 1);
        unsigned u = (unsigned)id >> 12;
        unsigned p = atomicAdd(&pos[v], 1u);
        packed[p] = ((unsigned)k << 12) | u;   // k in high 20 bits -> max(packed) == max(k)
        val[p] = make_float2(re[k], im[k]);
    }
}

// ================= 16-pt inverse FFT building blocks =================
__device__ __forceinline__ void bflyw(float2& a, float2& b, float wr, float wi) {
    float tr = b.x * wr - b.y * wi;
    float ti = b.x * wi + b.y * wr;
    b.x = a.x - tr; b.y = a.y - ti;
    a.x += tr; a.y += ti;
}
__device__ __forceinline__ void bfly1(float2& a, float2& b) {   // w = 1
    float tr = b.x, ti = b.y;
    b.x = a.x - tr; b.y = a.y - ti;
    a.x += tr; a.y += ti;
}
__device__ __forceinline__ void bflyI(float2& a, float2& b) {   // w = +i
    float tr = -b.y, ti = b.x;
    b.x = a.x - tr; b.y = a.y - ti;
    a.x += tr; a.y += ti;
}

#define C8f  0.70710678118654752f
#define C16f 0.92387953251128676f
#define S16f 0.38268343236508977f

// inverse 16-pt FFT (+i convention). Input in bit-reversed slots, output natural.
__device__ __forceinline__ void fft16(float2 r[16]) {
    bfly1(r[0], r[1]);  bfly1(r[2], r[3]);  bfly1(r[4], r[5]);   bfly1(r[6], r[7]);
    bfly1(r[8], r[9]);  bfly1(r[10], r[11]); bfly1(r[12], r[13]); bfly1(r[14], r[15]);
    bfly1(r[0], r[2]);  bflyI(r[1], r[3]);
    bfly1(r[4], r[6]);  bflyI(r[5], r[7]);
    bfly1(r[8], r[10]); bflyI(r[9], r[11]);
    bfly1(r[12], r[14]); bflyI(r[13], r[15]);
    bfly1(r[0], r[4]);  bflyw(r[1], r[5], C8f, C8f);  bflyI(r[2], r[6]);  bflyw(r[3], r[7], -C8f, C8f);
    bfly1(r[8], r[12]); bflyw(r[9], r[13], C8f, C8f); bflyI(r[10], r[14]); bflyw(r[11], r[15], -C8f, C8f);
    bfly1(r[0], r[8]);
    bflyw(r[1], r[9],  C16f, S16f);
    bflyw(r[2], r[10], C8f,  C8f);
    bflyw(r[3], r[11], S16f, C16f);
    bflyI(r[4], r[12]);
    bflyw(r[5], r[13], -S16f, C16f);
    bflyw(r[6], r[14], -C8f,  C8f);
    bflyw(r[7], r[15], -C16f, S16f);
}

// LDS XOR swizzle: bijective on [0,4096)
__device__ __forceinline__ int swz(int a) { return a ^ ((a >> 5) & 31); }

__device__ __forceinline__ void fft4096_lds(float* bre, float* bim, int t, float2 r[16],
                                            const int* rv) {
    // ---- phase 1: 16-pt over n1, column n2 = t ----
    #pragma unroll
    for (int n1 = 0; n1 < 16; ++n1) {
        int a = swz(256 * n1 + t);
        r[rv[n1]] = make_float2(bre[a], bim[a]);
    }
    fft16(r);
    {
        float s, c;
        sincosf((float)t * 1.5339807878856412e-3f, &s, &c);   // 2*pi/4096
        float2 w = make_float2(c, s), cur = make_float2(1.f, 0.f);
        #pragma unroll
        for (int k = 0; k < 16; ++k) {
            float xr = r[k].x * cur.x - r[k].y * cur.y;
            float xi = r[k].x * cur.y + r[k].y * cur.x;
            r[k].x = xr; r[k].y = xi;
            float nr = cur.x * w.x - cur.y * w.y;
            float ni = cur.x * w.y + cur.y * w.x;
            cur.x = nr; cur.y = ni;
        }
    }
    #pragma unroll
    for (int k = 0; k < 16; ++k) {
        int a = swz(256 * k + t);
        bre[a] = r[k].x; bim[a] = r[k].y;
    }
    __syncthreads();

    // ---- phase 2 ----
    const int k1 = t >> 4;
    const int lo = t & 15;
    const int base2 = 256 * k1 + lo;
    #pragma unroll
    for (int m1 = 0; m1 < 16; ++m1) {
        int a = swz(base2 + 16 * m1);
        r[rv[m1]] = make_float2(bre[a], bim[a]);
    }
    fft16(r);
    {
        float s, c;
        sincosf((float)lo * 2.45436926061702596e-2f, &s, &c); // 2*pi/256
        float2 w = make_float2(c, s), cur = make_float2(1.f, 0.f);
        #pragma unroll
        for (int k = 0; k < 16; ++k) {
            float xr = r[k].x * cur.x - r[k].y * cur.y;
            float xi = r[k].x * cur.y + r[k].y * cur.x;
            r[k].x = xr; r[k].y = xi;
            float nr = cur.x * w.x - cur.y * w.y;
            float ni = cur.x * w.y + cur.y * w.x;
            cur.x = nr; cur.y = ni;
        }
    }
    #pragma unroll
    for (int k = 0; k < 16; ++k) {
        int a = swz(base2 + 16 * k);
        bre[a] = r[k].x; bim[a] = r[k].y;
    }
    __syncthreads();

    // ---- phase 3 ----
    const int base3 = 256 * k1 + 16 * lo;
    #pragma unroll
    for (int m = 0; m < 16; ++m) {
        int a = swz(base3 + m);
        r[rv[m]] = make_float2(bre[a], bim[a]);
    }
    fft16(r);
    __syncthreads();   // all reads done before digit-swap scatter overwrites
}

// ---------------- pass 1: bucket-scatter into LDS + 4096-pt IFFT, complex out ----------------
// kwin ALIASES bre (both 16 KB) so total LDS stays 32 KB (5 blocks/CU).
__global__ void __launch_bounds__(256) ifft_pass1_kernel(const unsigned* __restrict__ start,
                                                         const unsigned* __restrict__ packed,
                                                         const float2* __restrict__ val,
                                                         float2* __restrict__ outp) {
    __shared__ float bre[FFT_N];
    __shared__ float bim[FFT_N];
    unsigned* kwin = (unsigned*)bre;   // alias: dead before bre is zero-filled
    const int t = threadIdx.x;
    const int v = blockIdx.x;

    const unsigned s0 = start[v], s1 = start[v + 1];

    // load this thread's bucket entries into registers (static indices after unroll)
    unsigned pk[4]; float2 wv[4]; bool vld[4]; bool win[4];
    #pragma unroll
    for (int e = 0; e < 4; ++e) {
        unsigned i = s0 + (unsigned)t + 256u * (unsigned)e;
        vld[e] = (i < s1);
        pk[e] = vld[e] ? packed[i] : 0u;
        wv[e] = vld[e] ? val[i] : make_float2(0.f, 0.f);
    }

    // winner resolution in kwin (aliasing bre)
    for (int j = t; j < FFT_N; j += 256) kwin[j] = 0u;
    __syncthreads();
    #pragma unroll
    for (int e = 0; e < 4; ++e)
        if (vld[e]) atomicMax(&kwin[pk[e] & 4095u], pk[e]);
    __syncthreads();
    #pragma unroll
    for (int e = 0; e < 4; ++e)
        win[e] = vld[e] && (kwin[pk[e] & 4095u] == pk[e]);
    __syncthreads();   // all kwin reads done before bre overwrites it

    for (int j = t; j < FFT_N; j += 256) { bre[j] = 0.f; bim[j] = 0.f; }
    __syncthreads();
    #pragma unroll
    for (int e = 0; e < 4; ++e)
        if (win[e]) {
            int a = swz((int)(pk[e] & 4095u));
            bre[a] = wv[e].x; bim[a] = wv[e].y;   // unique u among winners -> no races
        }
    __syncthreads();

    const int rv[16] = {0, 8, 4, 12, 2, 10, 6, 14, 1, 9, 5, 13, 3, 11, 7, 15};
    float2 r[16];
    fft4096_lds(bre, bim, t, r, rv);

    const float scale = 1.0f / 4096.0f;
    const int k1 = t >> 4, lo = t & 15;
    const int outb = k1 + 16 * lo;
    #pragma unroll
    for (int j2 = 0; j2 < 16; ++j2) {
        int a = swz(outb + 256 * j2);
        bre[a] = r[j2].x * scale;
        bim[a] = r[j2].y * scale;
    }
    __syncthreads();

    float2* __restrict__ og = outp + (size_t)v * FFT_N;
    for (int j = t; j < FFT_N; j += 256) {
        int a = swz(j);
        og[j] = make_float2(bre[a], bim[a]);
    }
}

// ---------------- pass 2: 4096-pt IFFT per row, real part -> bf16 ----------------
__global__ void __launch_bounds__(256) ifft_pass2_kernel(const float2* __restrict__ data,
                                                         __hip_bfloat16* __restrict__ wout) {
    __shared__ float bre[FFT_N];
    __shared__ float bim[FFT_N];
    const int t = threadIdx.x;
    const size_t rowoff = (size_t)blockIdx.x * FFT_N;
    const float2* __restrict__ g = data + rowoff;

    for (int j = t; j < FFT_N; j += 256) {
        float2 v = g[j];
        int a = swz(j);
        bre[a] = v.x; bim[a] = v.y;
    }
    __syncthreads();

    const int rv[16] = {0, 8, 4, 12, 2, 10, 6, 14, 1, 9, 5, 13, 3, 11, 7, 15};
    float2 r[16];
    fft4096_lds(bre, bim, t, r, rv);

    const float scale = 1.0f / 4096.0f;
    const int k1 = t >> 4, lo = t & 15;
    const int outb = k1 + 16 * lo;
    #pragma unroll
    for (int j2 = 0; j2 < 16; ++j2) {
        int a = swz(outb + 256 * j2);
        bre[a] = r[j2].x * scale;
    }
    __syncthreads();

    __hip_bfloat16* __restrict__ o = wout + rowoff;
    for (int j = t; j < FFT_N; j += 256) o[j] = __float2bfloat16(bre[swz(j)]);
}

// ---------------- in-place complex transpose (4096x4096 float2) ----------------
__global__ void transpose_kernel(float2* __restrict__ A) {
    const int bi = blockIdx.y, bj = blockIdx.x;
    if (bi > bj) return;
    __shared__ float2 tA[32][33];
    __shared__ float2 tB[32][33];
    const int tx = threadIdx.x;   // 0..31
    const int ty = threadIdx.y;   // 0..7
    #pragma unroll
    for (int k = 0; k < 4; ++k) {
        int r = ty + k * 8;
        tA[r][tx] = A[(size_t)(bi * 32 + r) * IN_F + bj * 32 + tx];
    }
    if (bi != bj) {
        #pragma unroll
        for (int k = 0; k < 4; ++k) {
            int r = ty + k * 8;
            tB[r][tx] = A[(size_t)(bj * 32 + r) * IN_F + bi * 32 + tx];
        }
    }
    __syncthreads();
    #pragma unroll
    for (int k = 0; k < 4; ++k) {
        int r = ty + k * 8;
        A[(size_t)(bj * 32 + r) * IN_F + bi * 32 + tx] = tA[tx][r];
    }
    if (bi != bj) {
        #pragma unroll
        for (int k = 0; k < 4; ++k) {
            int r = ty + k * 8;
            A[(size_t)(bi * 32 + r) * IN_F + bj * 32 + tx] = tB[tx][r];
        }
    }
}

// ---------------- f32 -> bf16 cast of x ----------------
__global__ void cast_x_kernel(const float4* __restrict__ x, ushort4* __restrict__ xb, int n4) {
    int i = blockIdx.x * blockDim.x + threadIdx.x;
    if (i < n4) {
        float4 v = x[i];
        __hip_bfloat16 a = __float2bfloat16(v.x);
        __hip_bfloat16 b = __float2bfloat16(v.y);
        __hip_bfloat16 c = __float2bfloat16(v.z);
        __hip_bfloat16 d = __float2bfloat16(v.w);
        ushort4 o;
        o.x = *reinterpret_cast<unsigned short*>(&a);
        o.y = *reinterpret_cast<unsigned short*>(&b);
        o.z = *reinterpret_cast<unsigned short*>(&c);
        o.w = *reinterpret_cast<unsigned short*>(&d);
        xb[i] = o;
    }
}

// ---------------- bf16 MFMA GEMM: out[M,N] = X[M,K] * W[N,K]^T + bias ----------------
__global__ void __launch_bounds__(256) gemm_kernel(const __hip_bfloat16* __restrict__ X,
                                                   const __hip_bfloat16* __restrict__ W,
                                                   const float* __restrict__ bias,
                                                   float* __restrict__ out) {
    __shared__ __align__(16) __hip_bfloat16 sA[128 * 32];   // 8 KB
    __shared__ __align__(16) __hip_bfloat16 sB[128 * 32];   // 8 KB
    const int tid = threadIdx.x;
    const int wv = tid >> 6;        // wave 0..3
    const int ln = tid & 63;
    const int m0 = blockIdx.y * 128;
    const int n0 = blockIdx.x * 128;
    const int wm = wv >> 1, wn = wv & 1;
    const int r16 = ln & 15, kg = ln >> 4;

    f32x4 acc[4][4];
    #pragma unroll
    for (int i = 0; i < 4; ++i)
        #pragma unroll
        for (int j = 0; j < 4; ++j) acc[i][j] = (f32x4){0.f, 0.f, 0.f, 0.f};

    for (int k0 = 0; k0 < IN_F; k0 += 32) {
        __syncthreads();
        #pragma unroll
        for (int c = 0; c < 2; ++c) {
            const int fc = (c * 4 + wv) * 64 + ln;   // chunk index 0..511
            const int row = fc >> 2;
            const int cc = fc & 3;
            const __hip_bfloat16* ga = X + (size_t)(m0 + row) * IN_F + k0 + cc * 8;
            __builtin_amdgcn_global_load_lds(
                (const __attribute__((address_space(1))) void*)ga,
                (__attribute__((address_space(3))) void*)(sA + (size_t)(c * 4 + wv) * 512),
                16, 0, 0);
            const __hip_bfloat16* gb = W + (size_t)(n0 + row) * IN_F + k0 + cc * 8;
            __builtin_amdgcn_global_load_lds(
                (const __attribute__((address_space(1))) void*)gb,
                (__attribute__((address_space(3))) void*)(sB + (size_t)(c * 4 + wv) * 512),
                16, 0, 0);
        }
        __syncthreads();

        bf16x8 af[4], bfr[4];
        #pragma unroll
        for (int i = 0; i < 4; ++i)
            af[i] = *reinterpret_cast<const bf16x8*>(&sA[(wm * 64 + i * 16 + r16) * 32 + kg * 8]);
        #pragma unroll
        for (int j = 0; j < 4; ++j)
            bfr[j] = *reinterpret_cast<const bf16x8*>(&sB[(wn * 64 + j * 16 + r16) * 32 + kg * 8]);
        #pragma unroll
        for (int i = 0; i < 4; ++i)
            #pragma unroll
            for (int j = 0; j < 4; ++j)
                acc[i][j] = __builtin_amdgcn_mfma_f32_16x16x32_bf16(af[i], bfr[j], acc[i][j], 0, 0, 0);
    }

    // epilogue: D[m][n], n = lane&15, m = (lane>>4)*4 + e
    #pragma unroll
    for (int i = 0; i < 4; ++i)
        #pragma unroll
        for (int j = 0; j < 4; ++j) {
            const int n = n0 + wn * 64 + j * 16 + r16;
            const float bs = bias[n];
            #pragma unroll
            for (int e = 0; e < 4; ++e) {
                const int m = m0 + wm * 64 + i * 16 + kg * 4 + e;
                out[(size_t)m * OUT_F + n] = acc[i][j][e] + bs;
            }
        }
}

extern "C" void kernel_launch(void* const* d_in, const int* in_sizes, int n_in,
                              void* d_out, int out_size, void* d_ws, size_t ws_size,
                              hipStream_t stream) {
    const float* x    = (const float*)d_in[0];
    const float* sre  = (const float*)d_in[1];
    const float* sim  = (const float*)d_in[2];
    const int*   sidx = (const int*)d_in[3];
    const float* bias = (const float*)d_in[4];
    const int nnz = in_sizes[1];
    float* out = (float*)d_out;

    char* ws = (char*)d_ws;
    // A (spectrum, complex, in-place FFT/transpose): 128 MiB @ 0
    float2* A = (float2*)ws;
    // bucket arrays alias the Wb region (dead before pass 2 writes Wb)
    unsigned* packed = (unsigned*)(ws + 134217728);                       // 4*nnz
    float2* bval = (float2*)(ws + 134217728 + 4194304);                   // 8*nnz
    __hip_bfloat16* Wb = (__hip_bfloat16*)(ws + 134217728);               // 33.5 MB (pass2 out)
    __hip_bfloat16* Xb = (__hip_bfloat16*)(ws + 134217728 + 33554432);    // 16.8 MB
    char* ctl = ws + 134217728 + 33554432 + 16777216;
    unsigned* cnt   = (unsigned*)(ctl);            // 4096
    unsigned* start = (unsigned*)(ctl + 32768);    // 4097
    unsigned* pos   = (unsigned*)(ctl + 65536);    // 4096

    hipMemsetAsync(cnt, 0, 4096 * sizeof(unsigned), stream);

    const int sb = (nnz + 255) / 256;
    hist_kernel<<<sb, 256, 0, stream>>>(sidx, cnt, nnz);
    scan_kernel<<<1, 256, 0, stream>>>(cnt, start, pos);
    bucket_scatter_kernel<<<sb, 256, 0, stream>>>(sidx, sre, sim, pos, packed, bval, nnz);

    // pass 1: scatter winners into LDS + ifft along original axis 0, rows = columns v
    ifft_pass1_kernel<<<FFT_N, 256, 0, stream>>>(start, packed, bval, A);
    // transpose so pass 2 is also row-wise
    transpose_kernel<<<dim3(128, 128), dim3(32, 8), 0, stream>>>(A);
    // pass 2: ifft along axis 1, real part -> bf16 weight [OUT_F][IN_F]
    ifft_pass2_kernel<<<FFT_N, 256, 0, stream>>>(A, Wb);

    cast_x_kernel<<<(MROWS * IN_F / 4 + 255) / 256, 256, 0, stream>>>(
        (const float4*)x, (ushort4*)Xb, MROWS * IN_F / 4);

    gemm_kernel<<<dim3(OUT_F / 128, MROWS / 128), 256, 0, stream>>>(Xb, Wb, bias, out);
}

// Round 5
// 342.356 us; speedup vs baseline: 1.0266x; 1.0098x over previous
//
#include <hip/hip_runtime.h>
#include <hip/hip_bf16.h>

#define OUT_F 4096
#define IN_F 4096
#define MROWS 2048            // 4*512 batch rows
#define FFT_N 4096

typedef short bf16x8 __attribute__((ext_vector_type(8)));
typedef float f32x4 __attribute__((ext_vector_type(4)));

// ================= bucket build (counting sort by column v) =================
__global__ void hist_kernel(const int* __restrict__ idx, unsigned* __restrict__ cnt, int nnz) {
    int k = blockIdx.x * blockDim.x + threadIdx.x;
    if (k < nnz) atomicAdd(&cnt[idx[k] & (IN_F - 1)], 1u);
}

__global__ void __launch_bounds__(256) scan_kernel(const unsigned* __restrict__ cnt,
                                                   unsigned* __restrict__ start,
                                                   unsigned* __restrict__ pos) {
    __shared__ unsigned part[257];
    const int t = threadIdx.x;
    unsigned s = 0;
    #pragma unroll
    for (int j = 0; j < 16; ++j) s += cnt[t * 16 + j];
    part[t + 1] = s;
    if (t == 0) part[0] = 0;
    __syncthreads();
    if (t == 0)
        for (int i = 1; i <= 256; ++i) part[i] += part[i - 1];
    __syncthreads();
    unsigned run = part[t];
    #pragma unroll
    for (int j = 0; j < 16; ++j) {
        start[t * 16 + j] = run;
        pos[t * 16 + j] = run;
        run += cnt[t * 16 + j];
    }
    if (t == 255) start[4096] = run;
}

__global__ void bucket_scatter_kernel(const int* __restrict__ idx, const float* __restrict__ re,
                                      const float* __restrict__ im, unsigned* __restrict__ pos,
                                      unsigned* __restrict__ packed, float2* __restrict__ val,
                                      int nnz) {
    int k = blockIdx.x * blockDim.x + threadIdx.x;
    if (k < nnz) {
        int id = idx[k];
        unsigned v = (unsigned)id & (IN_F - 1);
        unsigned u = (unsigned)id >> 12;
        unsigned p = atomicAdd(&pos[v], 1u);
        packed[p] = ((unsigned)k << 12) | u;   // k in high 20 bits -> max(packed) == max(k)
        val[p] = make_float2(re[k], im[k]);
    }
}

// ================= 16-pt inverse FFT building blocks =================
__device__ __forceinline__ void bflyw(float2& a, float2& b, float wr, float wi) {
    float tr = b.x * wr - b.y * wi;
    float ti = b.x * wi + b.y * wr;
    b.x = a.x - tr; b.y = a.y - ti;
    a.x += tr; a.y += ti;
}
__device__ __forceinline__ void bfly1(float2& a, float2& b) {   // w = 1
    float tr = b.x, ti = b.y;
    b.x = a.x - tr; b.y = a.y - ti;
    a.x += tr; a.y += ti;
}
__device__ __forceinline__ void bflyI(float2& a, float2& b) {   // w = +i
    float tr = -b.y, ti = b.x;
    b.x = a.x - tr; b.y = a.y - ti;
    a.x += tr; a.y += ti;
}

#define C8f  0.70710678118654752f
#define C16f 0.92387953251128676f
#define S16f 0.38268343236508977f

// inverse 16-pt FFT (+i convention). Input in bit-reversed slots, output natural.
__device__ __forceinline__ void fft16(float2 r[16]) {
    bfly1(r[0], r[1]);  bfly1(r[2], r[3]);  bfly1(r[4], r[5]);   bfly1(r[6], r[7]);
    bfly1(r[8], r[9]);  bfly1(r[10], r[11]); bfly1(r[12], r[13]); bfly1(r[14], r[15]);
    bfly1(r[0], r[2]);  bflyI(r[1], r[3]);
    bfly1(r[4], r[6]);  bflyI(r[5], r[7]);
    bfly1(r[8], r[10]); bflyI(r[9], r[11]);
    bfly1(r[12], r[14]); bflyI(r[13], r[15]);
    bfly1(r[0], r[4]);  bflyw(r[1], r[5], C8f, C8f);  bflyI(r[2], r[6]);  bflyw(r[3], r[7], -C8f, C8f);
    bfly1(r[8], r[12]); bflyw(r[9], r[13], C8f, C8f); bflyI(r[10], r[14]); bflyw(r[11], r[15], -C8f, C8f);
    bfly1(r[0], r[8]);
    bflyw(r[1], r[9],  C16f, S16f);
    bflyw(r[2], r[10], C8f,  C8f);
    bflyw(r[3], r[11], S16f, C16f);
    bflyI(r[4], r[12]);
    bflyw(r[5], r[13], -S16f, C16f);
    bflyw(r[6], r[14], -C8f,  C8f);
    bflyw(r[7], r[15], -C16f, S16f);
}

// LDS XOR swizzle: bijective on [0,4096)
__device__ __forceinline__ int swz(int a) { return a ^ ((a >> 5) & 31); }

__device__ __forceinline__ void fft4096_lds(float* bre, float* bim, int t, float2 r[16],
                                            const int* rv) {
    // ---- phase 1: 16-pt over n1, column n2 = t ----
    #pragma unroll
    for (int n1 = 0; n1 < 16; ++n1) {
        int a = swz(256 * n1 + t);
        r[rv[n1]] = make_float2(bre[a], bim[a]);
    }
    fft16(r);
    {
        float s, c;
        sincosf((float)t * 1.5339807878856412e-3f, &s, &c);   // 2*pi/4096
        float2 w = make_float2(c, s), cur = make_float2(1.f, 0.f);
        #pragma unroll
        for (int k = 0; k < 16; ++k) {
            float xr = r[k].x * cur.x - r[k].y * cur.y;
            float xi = r[k].x * cur.y + r[k].y * cur.x;
            r[k].x = xr; r[k].y = xi;
            float nr = cur.x * w.x - cur.y * w.y;
            float ni = cur.x * w.y + cur.y * w.x;
            cur.x = nr; cur.y = ni;
        }
    }
    #pragma unroll
    for (int k = 0; k < 16; ++k) {
        int a = swz(256 * k + t);
        bre[a] = r[k].x; bim[a] = r[k].y;
    }
    __syncthreads();

    // ---- phase 2 ----
    const int k1 = t >> 4;
    const int lo = t & 15;
    const int base2 = 256 * k1 + lo;
    #pragma unroll
    for (int m1 = 0; m1 < 16; ++m1) {
        int a = swz(base2 + 16 * m1);
        r[rv[m1]] = make_float2(bre[a], bim[a]);
    }
    fft16(r);
    {
        float s, c;
        sincosf((float)lo * 2.45436926061702596e-2f, &s, &c); // 2*pi/256
        float2 w = make_float2(c, s), cur = make_float2(1.f, 0.f);
        #pragma unroll
        for (int k = 0; k < 16; ++k) {
            float xr = r[k].x * cur.x - r[k].y * cur.y;
            float xi = r[k].x * cur.y + r[k].y * cur.x;
            r[k].x = xr; r[k].y = xi;
            float nr = cur.x * w.x - cur.y * w.y;
            float ni = cur.x * w.y + cur.y * w.x;
            cur.x = nr; cur.y = ni;
        }
    }
    #pragma unroll
    for (int k = 0; k < 16; ++k) {
        int a = swz(base2 + 16 * k);
        bre[a] = r[k].x; bim[a] = r[k].y;
    }
    __syncthreads();

    // ---- phase 3 ----
    const int base3 = 256 * k1 + 16 * lo;
    #pragma unroll
    for (int m = 0; m < 16; ++m) {
        int a = swz(base3 + m);
        r[rv[m]] = make_float2(bre[a], bim[a]);
    }
    fft16(r);
    __syncthreads();   // all reads done before digit-swap scatter overwrites
}

// ---------------- pass 1: bucket-scatter into LDS + 4096-pt IFFT ----------------
// Output written TILED: B'[u>>6][v][u&63] so pass 2's column read stays in one
// 2 MB panel. kwin ALIASES bre so LDS stays 32 KB.
__global__ void __launch_bounds__(256) ifft_pass1_kernel(const unsigned* __restrict__ start,
                                                         const unsigned* __restrict__ packed,
                                                         const float2* __restrict__ val,
                                                         float2* __restrict__ outp) {
    __shared__ float bre[FFT_N];
    __shared__ float bim[FFT_N];
    unsigned* kwin = (unsigned*)bre;   // alias: dead before bre is zero-filled
    const int t = threadIdx.x;
    const int v = blockIdx.x;

    const unsigned s0 = start[v], s1 = start[v + 1];

    // load this thread's bucket entries into registers (static indices after unroll)
    unsigned pk[4]; float2 wv[4]; bool vld[4]; bool win[4];
    #pragma unroll
    for (int e = 0; e < 4; ++e) {
        unsigned i = s0 + (unsigned)t + 256u * (unsigned)e;
        vld[e] = (i < s1);
        pk[e] = vld[e] ? packed[i] : 0u;
        wv[e] = vld[e] ? val[i] : make_float2(0.f, 0.f);
    }

    // winner resolution in kwin (aliasing bre)
    for (int j = t; j < FFT_N; j += 256) kwin[j] = 0u;
    __syncthreads();
    #pragma unroll
    for (int e = 0; e < 4; ++e)
        if (vld[e]) atomicMax(&kwin[pk[e] & 4095u], pk[e]);
    __syncthreads();
    #pragma unroll
    for (int e = 0; e < 4; ++e)
        win[e] = vld[e] && (kwin[pk[e] & 4095u] == pk[e]);
    __syncthreads();   // all kwin reads done before bre overwrites it

    for (int j = t; j < FFT_N; j += 256) { bre[j] = 0.f; bim[j] = 0.f; }
    __syncthreads();
    #pragma unroll
    for (int e = 0; e < 4; ++e)
        if (win[e]) {
            int a = swz((int)(pk[e] & 4095u));
            bre[a] = wv[e].x; bim[a] = wv[e].y;   // unique u among winners -> no races
        }
    __syncthreads();

    const int rv[16] = {0, 8, 4, 12, 2, 10, 6, 14, 1, 9, 5, 13, 3, 11, 7, 15};
    float2 r[16];
    fft4096_lds(bre, bim, t, r, rv);

    const float scale = 1.0f / 4096.0f;
    const int k1 = t >> 4, lo = t & 15;
    const int outb = k1 + 16 * lo;
    #pragma unroll
    for (int j2 = 0; j2 < 16; ++j2) {
        int a = swz(outb + 256 * j2);
        bre[a] = r[j2].x * scale;
        bim[a] = r[j2].y * scale;
    }
    __syncthreads();

    // tiled write: element (v, j) -> B'[(j>>6)*4096 + v][j&63]
    // lanes j..j+63 -> contiguous 512 B within one panel row: coalesced
    for (int j = t; j < FFT_N; j += 256) {
        int a = swz(j);
        outp[((size_t)(j >> 6) * FFT_N + v) * 64 + (j & 63)] = make_float2(bre[a], bim[a]);
    }
}

// ---------------- pass 2: 4096-pt IFFT per column (tiled read), real -> bf16 ----------------
// Block handles output row u. Reads B'[u>>6][v][u&63] for v=0..4095: stride-512B
// within a 2 MB panel shared by the 64 blocks with equal u>>6. XCD-chunked
// mapping keeps those 64 blocks on one XCD so L2 serves the 8-u/line reuse.
__global__ void __launch_bounds__(256) ifft_pass2_kernel(const float2* __restrict__ data,
                                                         __hip_bfloat16* __restrict__ wout) {
    __shared__ float bre[FFT_N];
    __shared__ float bim[FFT_N];
    const int t = threadIdx.x;
    const int bid = blockIdx.x;
    // bid -> u: XCD x = bid&7 owns u in [x*512, x*512+512), walked panel-by-panel
    const int x = bid & 7, s = bid >> 3;
    const int u = x * 512 + ((s >> 6) << 6) + (s & 63);
    const float2* __restrict__ gp = data + ((size_t)(u >> 6) * FFT_N) * 64 + (u & 63);

    for (int j = t; j < FFT_N; j += 256) {
        float2 v2 = gp[(size_t)j * 64];
        int a = swz(j);
        bre[a] = v2.x; bim[a] = v2.y;
    }
    __syncthreads();

    const int rv[16] = {0, 8, 4, 12, 2, 10, 6, 14, 1, 9, 5, 13, 3, 11, 7, 15};
    float2 r[16];
    fft4096_lds(bre, bim, t, r, rv);

    const float scale = 1.0f / 4096.0f;
    const int k1 = t >> 4, lo = t & 15;
    const int outb = k1 + 16 * lo;
    #pragma unroll
    for (int j2 = 0; j2 < 16; ++j2) {
        int a = swz(outb + 256 * j2);
        bre[a] = r[j2].x * scale;
    }
    __syncthreads();

    __hip_bfloat16* __restrict__ o = wout + (size_t)u * FFT_N;
    for (int j = t; j < FFT_N; j += 256) o[j] = __float2bfloat16(bre[swz(j)]);
}

// ---------------- f32 -> bf16 cast of x ----------------
__global__ void cast_x_kernel(const float4* __restrict__ x, ushort4* __restrict__ xb, int n4) {
    int i = blockIdx.x * blockDim.x + threadIdx.x;
    if (i < n4) {
        float4 v = x[i];
        __hip_bfloat16 a = __float2bfloat16(v.x);
        __hip_bfloat16 b = __float2bfloat16(v.y);
        __hip_bfloat16 c = __float2bfloat16(v.z);
        __hip_bfloat16 d = __float2bfloat16(v.w);
        ushort4 o;
        o.x = *reinterpret_cast<unsigned short*>(&a);
        o.y = *reinterpret_cast<unsigned short*>(&b);
        o.z = *reinterpret_cast<unsigned short*>(&c);
        o.w = *reinterpret_cast<unsigned short*>(&d);
        xb[i] = o;
    }
}

// ---------------- bf16 MFMA GEMM: out[M,N] = X[M,K] * W[N,K]^T + bias ----------------
__global__ void __launch_bounds__(256) gemm_kernel(const __hip_bfloat16* __restrict__ X,
                                                   const __hip_bfloat16* __restrict__ W,
                                                   const float* __restrict__ bias,
                                                   float* __restrict__ out) {
    __shared__ __align__(16) __hip_bfloat16 sA[128 * 32];   // 8 KB
    __shared__ __align__(16) __hip_bfloat16 sB[128 * 32];   // 8 KB
    const int tid = threadIdx.x;
    const int wv = tid >> 6;        // wave 0..3
    const int ln = tid & 63;
    const int m0 = blockIdx.y * 128;
    const int n0 = blockIdx.x * 128;
    const int wm = wv >> 1, wn = wv & 1;
    const int r16 = ln & 15, kg = ln >> 4;

    f32x4 acc[4][4];
    #pragma unroll
    for (int i = 0; i < 4; ++i)
        #pragma unroll
        for (int j = 0; j < 4; ++j) acc[i][j] = (f32x4){0.f, 0.f, 0.f, 0.f};

    for (int k0 = 0; k0 < IN_F; k0 += 32) {
        __syncthreads();
        #pragma unroll
        for (int c = 0; c < 2; ++c) {
            const int fc = (c * 4 + wv) * 64 + ln;   // chunk index 0..511
            const int row = fc >> 2;
            const int cc = fc & 3;
            const __hip_bfloat16* ga = X + (size_t)(m0 + row) * IN_F + k0 + cc * 8;
            __builtin_amdgcn_global_load_lds(
                (const __attribute__((address_space(1))) void*)ga,
                (__attribute__((address_space(3))) void*)(sA + (size_t)(c * 4 + wv) * 512),
                16, 0, 0);
            const __hip_bfloat16* gb = W + (size_t)(n0 + row) * IN_F + k0 + cc * 8;
            __builtin_amdgcn_global_load_lds(
                (const __attribute__((address_space(1))) void*)gb,
                (__attribute__((address_space(3))) void*)(sB + (size_t)(c * 4 + wv) * 512),
                16, 0, 0);
        }
        __syncthreads();

        bf16x8 af[4], bfr[4];
        #pragma unroll
        for (int i = 0; i < 4; ++i)
            af[i] = *reinterpret_cast<const bf16x8*>(&sA[(wm * 64 + i * 16 + r16) * 32 + kg * 8]);
        #pragma unroll
        for (int j = 0; j < 4; ++j)
            bfr[j] = *reinterpret_cast<const bf16x8*>(&sB[(wn * 64 + j * 16 + r16) * 32 + kg * 8]);
        #pragma unroll
        for (int i = 0; i < 4; ++i)
            #pragma unroll
            for (int j = 0; j < 4; ++j)
                acc[i][j] = __builtin_amdgcn_mfma_f32_16x16x32_bf16(af[i], bfr[j], acc[i][j], 0, 0, 0);
    }

    // epilogue: D[m][n], n = lane&15, m = (lane>>4)*4 + e
    #pragma unroll
    for (int i = 0; i < 4; ++i)
        #pragma unroll
        for (int j = 0; j < 4; ++j) {
            const int n = n0 + wn * 64 + j * 16 + r16;
            const float bs = bias[n];
            #pragma unroll
            for (int e = 0; e < 4; ++e) {
                const int m = m0 + wm * 64 + i * 16 + kg * 4 + e;
                out[(size_t)m * OUT_F + n] = acc[i][j][e] + bs;
            }
        }
}

extern "C" void kernel_launch(void* const* d_in, const int* in_sizes, int n_in,
                              void* d_out, int out_size, void* d_ws, size_t ws_size,
                              hipStream_t stream) {
    const float* x    = (const float*)d_in[0];
    const float* sre  = (const float*)d_in[1];
    const float* sim  = (const float*)d_in[2];
    const int*   sidx = (const int*)d_in[3];
    const float* bias = (const float*)d_in[4];
    const int nnz = in_sizes[1];
    float* out = (float*)d_out;

    char* ws = (char*)d_ws;
    // A (tiled intermediate B'): 128 MiB @ 0
    float2* A = (float2*)ws;
    // bucket arrays alias the Wb region (dead before pass 2 writes Wb)
    unsigned* packed = (unsigned*)(ws + 134217728);                       // 4*nnz
    float2* bval = (float2*)(ws + 134217728 + 4194304);                   // 8*nnz
    __hip_bfloat16* Wb = (__hip_bfloat16*)(ws + 134217728);               // 33.5 MB (pass2 out)
    __hip_bfloat16* Xb = (__hip_bfloat16*)(ws + 134217728 + 33554432);    // 16.8 MB
    char* ctl = ws + 134217728 + 33554432 + 16777216;
    unsigned* cnt   = (unsigned*)(ctl);            // 4096
    unsigned* start = (unsigned*)(ctl + 32768);    // 4097
    unsigned* pos   = (unsigned*)(ctl + 65536);    // 4096

    hipMemsetAsync(cnt, 0, 4096 * sizeof(unsigned), stream);

    const int sb = (nnz + 255) / 256;
    hist_kernel<<<sb, 256, 0, stream>>>(sidx, cnt, nnz);
    scan_kernel<<<1, 256, 0, stream>>>(cnt, start, pos);
    bucket_scatter_kernel<<<sb, 256, 0, stream>>>(sidx, sre, sim, pos, packed, bval, nnz);

    // pass 1: scatter winners into LDS + ifft along original axis 0; tiled output
    ifft_pass1_kernel<<<FFT_N, 256, 0, stream>>>(start, packed, bval, A);
    // pass 2: ifft along axis 1 via tiled column reads, real part -> bf16 weight
    ifft_pass2_kernel<<<FFT_N, 256, 0, stream>>>(A, Wb);

    cast_x_kernel<<<(MROWS * IN_F / 4 + 255) / 256, 256, 0, stream>>>(
        (const float4*)x, (ushort4*)Xb, MROWS * IN_F / 4);

    gemm_kernel<<<dim3(OUT_F / 128, MROWS / 128), 256, 0, stream>>>(Xb, Wb, bias, out);
}

// Round 6
// 309.964 us; speedup vs baseline: 1.1339x; 1.1045x over previous
//
#include <hip/hip_runtime.h>
#include <hip/hip_bf16.h>

#define OUT_F 4096
#define IN_F 4096
#define MROWS 2048            // 4*512 batch rows
#define FFT_N 4096

typedef short bf16x8 __attribute__((ext_vector_type(8)));
typedef float f32x4 __attribute__((ext_vector_type(4)));

// ================= bucket build (counting sort by column v) =================
__global__ void hist_kernel(const int* __restrict__ idx, unsigned* __restrict__ cnt, int nnz) {
    int k = blockIdx.x * blockDim.x + threadIdx.x;
    if (k < nnz) atomicAdd(&cnt[idx[k] & (IN_F - 1)], 1u);
}

__global__ void __launch_bounds__(256) scan_kernel(const unsigned* __restrict__ cnt,
                                                   unsigned* __restrict__ start,
                                                   unsigned* __restrict__ pos) {
    __shared__ unsigned part[257];
    const int t = threadIdx.x;
    unsigned s = 0;
    #pragma unroll
    for (int j = 0; j < 16; ++j) s += cnt[t * 16 + j];
    part[t + 1] = s;
    if (t == 0) part[0] = 0;
    __syncthreads();
    if (t == 0)
        for (int i = 1; i <= 256; ++i) part[i] += part[i - 1];
    __syncthreads();
    unsigned run = part[t];
    #pragma unroll
    for (int j = 0; j < 16; ++j) {
        start[t * 16 + j] = run;
        pos[t * 16 + j] = run;
        run += cnt[t * 16 + j];
    }
    if (t == 255) start[4096] = run;
}

__global__ void bucket_scatter_kernel(const int* __restrict__ idx, const float* __restrict__ re,
                                      const float* __restrict__ im, unsigned* __restrict__ pos,
                                      unsigned* __restrict__ packed, float2* __restrict__ val,
                                      int nnz) {
    int k = blockIdx.x * blockDim.x + threadIdx.x;
    if (k < nnz) {
        int id = idx[k];
        unsigned v = (unsigned)id & (IN_F - 1);
        unsigned u = (unsigned)id >> 12;
        unsigned p = atomicAdd(&pos[v], 1u);
        packed[p] = ((unsigned)k << 12) | u;   // k in high 20 bits -> max(packed) == max(k)
        val[p] = make_float2(re[k], im[k]);
    }
}

// ================= 16-pt inverse FFT building blocks =================
__device__ __forceinline__ void bflyw(float2& a, float2& b, float wr, float wi) {
    float tr = b.x * wr - b.y * wi;
    float ti = b.x * wi + b.y * wr;
    b.x = a.x - tr; b.y = a.y - ti;
    a.x += tr; a.y += ti;
}
__device__ __forceinline__ void bfly1(float2& a, float2& b) {   // w = 1
    float tr = b.x, ti = b.y;
    b.x = a.x - tr; b.y = a.y - ti;
    a.x += tr; a.y += ti;
}
__device__ __forceinline__ void bflyI(float2& a, float2& b) {   // w = +i
    float tr = -b.y, ti = b.x;
    b.x = a.x - tr; b.y = a.y - ti;
    a.x += tr; a.y += ti;
}

#define C8f  0.70710678118654752f
#define C16f 0.92387953251128676f
#define S16f 0.38268343236508977f

// inverse 16-pt FFT (+i convention). Input in bit-reversed slots, output natural.
__device__ __forceinline__ void fft16(float2 r[16]) {
    bfly1(r[0], r[1]);  bfly1(r[2], r[3]);  bfly1(r[4], r[5]);   bfly1(r[6], r[7]);
    bfly1(r[8], r[9]);  bfly1(r[10], r[11]); bfly1(r[12], r[13]); bfly1(r[14], r[15]);
    bfly1(r[0], r[2]);  bflyI(r[1], r[3]);
    bfly1(r[4], r[6]);  bflyI(r[5], r[7]);
    bfly1(r[8], r[10]); bflyI(r[9], r[11]);
    bfly1(r[12], r[14]); bflyI(r[13], r[15]);
    bfly1(r[0], r[4]);  bflyw(r[1], r[5], C8f, C8f);  bflyI(r[2], r[6]);  bflyw(r[3], r[7], -C8f, C8f);
    bfly1(r[8], r[12]); bflyw(r[9], r[13], C8f, C8f); bflyI(r[10], r[14]); bflyw(r[11], r[15], -C8f, C8f);
    bfly1(r[0], r[8]);
    bflyw(r[1], r[9],  C16f, S16f);
    bflyw(r[2], r[10], C8f,  C8f);
    bflyw(r[3], r[11], S16f, C16f);
    bflyI(r[4], r[12]);
    bflyw(r[5], r[13], -S16f, C16f);
    bflyw(r[6], r[14], -C8f,  C8f);
    bflyw(r[7], r[15], -C16f, S16f);
}

// LDS XOR swizzle: bijective on [0,4096)
__device__ __forceinline__ int swz(int a) { return a ^ ((a >> 5) & 31); }

__device__ __forceinline__ void fft4096_lds(float* bre, float* bim, int t, float2 r[16],
                                            const int* rv) {
    // ---- phase 1: 16-pt over n1, column n2 = t ----
    #pragma unroll
    for (int n1 = 0; n1 < 16; ++n1) {
        int a = swz(256 * n1 + t);
        r[rv[n1]] = make_float2(bre[a], bim[a]);
    }
    fft16(r);
    {
        float s, c;
        sincosf((float)t * 1.5339807878856412e-3f, &s, &c);   // 2*pi/4096
        float2 w = make_float2(c, s), cur = make_float2(1.f, 0.f);
        #pragma unroll
        for (int k = 0; k < 16; ++k) {
            float xr = r[k].x * cur.x - r[k].y * cur.y;
            float xi = r[k].x * cur.y + r[k].y * cur.x;
            r[k].x = xr; r[k].y = xi;
            float nr = cur.x * w.x - cur.y * w.y;
            float ni = cur.x * w.y + cur.y * w.x;
            cur.x = nr; cur.y = ni;
        }
    }
    #pragma unroll
    for (int k = 0; k < 16; ++k) {
        int a = swz(256 * k + t);
        bre[a] = r[k].x; bim[a] = r[k].y;
    }
    __syncthreads();

    // ---- phase 2 ----
    const int k1 = t >> 4;
    const int lo = t & 15;
    const int base2 = 256 * k1 + lo;
    #pragma unroll
    for (int m1 = 0; m1 < 16; ++m1) {
        int a = swz(base2 + 16 * m1);
        r[rv[m1]] = make_float2(bre[a], bim[a]);
    }
    fft16(r);
    {
        float s, c;
        sincosf((float)lo * 2.45436926061702596e-2f, &s, &c); // 2*pi/256
        float2 w = make_float2(c, s), cur = make_float2(1.f, 0.f);
        #pragma unroll
        for (int k = 0; k < 16; ++k) {
            float xr = r[k].x * cur.x - r[k].y * cur.y;
            float xi = r[k].x * cur.y + r[k].y * cur.x;
            r[k].x = xr; r[k].y = xi;
            float nr = cur.x * w.x - cur.y * w.y;
            float ni = cur.x * w.y + cur.y * w.x;
            cur.x = nr; cur.y = ni;
        }
    }
    #pragma unroll
    for (int k = 0; k < 16; ++k) {
        int a = swz(base2 + 16 * k);
        bre[a] = r[k].x; bim[a] = r[k].y;
    }
    __syncthreads();

    // ---- phase 3 ----
    const int base3 = 256 * k1 + 16 * lo;
    #pragma unroll
    for (int m = 0; m < 16; ++m) {
        int a = swz(base3 + m);
        r[rv[m]] = make_float2(bre[a], bim[a]);
    }
    fft16(r);
    __syncthreads();   // all reads done before digit-swap scatter overwrites
}

// ---------------- pass 1: bucket-scatter into LDS + 4096-pt IFFT ----------------
// Output written TILED, width 8: B'[u>>3][v][u&7] — one 64-B line holds the 8
// sibling u-columns, so pass 2 reads full lines. kwin ALIASES bre (32 KB LDS).
__global__ void __launch_bounds__(256) ifft_pass1_kernel(const unsigned* __restrict__ start,
                                                         const unsigned* __restrict__ packed,
                                                         const float2* __restrict__ val,
                                                         float2* __restrict__ outp) {
    __shared__ float bre[FFT_N];
    __shared__ float bim[FFT_N];
    unsigned* kwin = (unsigned*)bre;   // alias: dead before bre is zero-filled
    const int t = threadIdx.x;
    const int v = blockIdx.x;

    const unsigned s0 = start[v], s1 = start[v + 1];

    // load this thread's bucket entries into registers (static indices after unroll)
    unsigned pk[4]; float2 wv[4]; bool vld[4]; bool win[4];
    #pragma unroll
    for (int e = 0; e < 4; ++e) {
        unsigned i = s0 + (unsigned)t + 256u * (unsigned)e;
        vld[e] = (i < s1);
        pk[e] = vld[e] ? packed[i] : 0u;
        wv[e] = vld[e] ? val[i] : make_float2(0.f, 0.f);
    }

    // winner resolution in kwin (aliasing bre)
    for (int j = t; j < FFT_N; j += 256) kwin[j] = 0u;
    __syncthreads();
    #pragma unroll
    for (int e = 0; e < 4; ++e)
        if (vld[e]) atomicMax(&kwin[pk[e] & 4095u], pk[e]);
    __syncthreads();
    #pragma unroll
    for (int e = 0; e < 4; ++e)
        win[e] = vld[e] && (kwin[pk[e] & 4095u] == pk[e]);
    __syncthreads();   // all kwin reads done before bre overwrites it

    for (int j = t; j < FFT_N; j += 256) { bre[j] = 0.f; bim[j] = 0.f; }
    __syncthreads();
    #pragma unroll
    for (int e = 0; e < 4; ++e)
        if (win[e]) {
            int a = swz((int)(pk[e] & 4095u));
            bre[a] = wv[e].x; bim[a] = wv[e].y;   // unique u among winners -> no races
        }
    __syncthreads();

    const int rv[16] = {0, 8, 4, 12, 2, 10, 6, 14, 1, 9, 5, 13, 3, 11, 7, 15};
    float2 r[16];
    fft4096_lds(bre, bim, t, r, rv);

    const float scale = 1.0f / 4096.0f;
    const int k1 = t >> 4, lo = t & 15;
    const int outb = k1 + 16 * lo;
    #pragma unroll
    for (int j2 = 0; j2 < 16; ++j2) {
        int a = swz(outb + 256 * j2);
        bre[a] = r[j2].x * scale;
        bim[a] = r[j2].y * scale;
    }
    __syncthreads();

    // tiled write: element (v, j) -> B'[(j>>3)*4096 + v][j&7]
    // 8 lanes cover one full 64-B line; each wave writes 8 full lines
    for (int j = t; j < FFT_N; j += 256) {
        int a = swz(j);
        outp[((size_t)(j >> 3) * FFT_N + v) * 8 + (j & 7)] = make_float2(bre[a], bim[a]);
    }
}

// ---------------- pass 2: 4096-pt IFFT per column (tiled read), real -> bf16 ----------------
// Block handles output row u. Reads B'[u>>3][v][u&7]: a wave's 64 lanes read a
// CONTIGUOUS 4 KB region; the 8 blocks sharing a 256 KB panel (same u>>3) are
// co-dispatched on one XCD via u = (bid&7)*512 + (bid>>3).
__global__ void __launch_bounds__(256) ifft_pass2_kernel(const float2* __restrict__ data,
                                                         __hip_bfloat16* __restrict__ wout) {
    __shared__ float bre[FFT_N];
    __shared__ float bim[FFT_N];
    const int t = threadIdx.x;
    const int bid = blockIdx.x;
    const int u = (bid & 7) * 512 + (bid >> 3);
    const float2* __restrict__ gp = data + (size_t)(u >> 3) * FFT_N * 8 + (u & 7);

    for (int j = t; j < FFT_N; j += 256) {
        float2 v2 = gp[(size_t)j * 8];
        int a = swz(j);
        bre[a] = v2.x; bim[a] = v2.y;
    }
    __syncthreads();

    const int rv[16] = {0, 8, 4, 12, 2, 10, 6, 14, 1, 9, 5, 13, 3, 11, 7, 15};
    float2 r[16];
    fft4096_lds(bre, bim, t, r, rv);

    const float scale = 1.0f / 4096.0f;
    const int k1 = t >> 4, lo = t & 15;
    const int outb = k1 + 16 * lo;
    #pragma unroll
    for (int j2 = 0; j2 < 16; ++j2) {
        int a = swz(outb + 256 * j2);
        bre[a] = r[j2].x * scale;
    }
    __syncthreads();

    __hip_bfloat16* __restrict__ o = wout + (size_t)u * FFT_N;
    for (int j = t; j < FFT_N; j += 256) o[j] = __float2bfloat16(bre[swz(j)]);
}

// ---------------- f32 -> bf16 cast of x ----------------
__global__ void cast_x_kernel(const float4* __restrict__ x, ushort4* __restrict__ xb, int n4) {
    int i = blockIdx.x * blockDim.x + threadIdx.x;
    if (i < n4) {
        float4 v = x[i];
        __hip_bfloat16 a = __float2bfloat16(v.x);
        __hip_bfloat16 b = __float2bfloat16(v.y);
        __hip_bfloat16 c = __float2bfloat16(v.z);
        __hip_bfloat16 d = __float2bfloat16(v.w);
        ushort4 o;
        o.x = *reinterpret_cast<unsigned short*>(&a);
        o.y = *reinterpret_cast<unsigned short*>(&b);
        o.z = *reinterpret_cast<unsigned short*>(&c);
        o.w = *reinterpret_cast<unsigned short*>(&d);
        xb[i] = o;
    }
}

// ---------------- bf16 MFMA GEMM: out[M,N] = X[M,K] * W[N,K]^T + bias ----------------
// BK=64; T2 XOR-swizzle applied via pre-swizzled GLOBAL source (linear
// global_load_lds dest) + swizzled ds_read: LDS chunk p of row holds logical
// k-chunk p ^ (row&7). 32 MFMAs per barrier pair (2x the BK=32 version).
__global__ void __launch_bounds__(256) gemm_kernel(const __hip_bfloat16* __restrict__ X,
                                                   const __hip_bfloat16* __restrict__ W,
                                                   const float* __restrict__ bias,
                                                   float* __restrict__ out) {
    __shared__ __align__(16) __hip_bfloat16 sA[128 * 64];   // 16 KB
    __shared__ __align__(16) __hip_bfloat16 sB[128 * 64];   // 16 KB
    const int tid = threadIdx.x;
    const int wv = tid >> 6;        // wave 0..3
    const int ln = tid & 63;
    const int m0 = blockIdx.y * 128;
    const int n0 = blockIdx.x * 128;
    const int wm = wv >> 1, wn = wv & 1;
    const int r16 = ln & 15, kg = ln >> 4;

    f32x4 acc[4][4];
    #pragma unroll
    for (int i = 0; i < 4; ++i)
        #pragma unroll
        for (int j = 0; j < 4; ++j) acc[i][j] = (f32x4){0.f, 0.f, 0.f, 0.f};

    for (int k0 = 0; k0 < IN_F; k0 += 64) {
        __syncthreads();
        #pragma unroll
        for (int c = 0; c < 4; ++c) {
            const int fc = (c * 4 + wv) * 64 + ln;   // chunk slot 0..1023
            const int row = fc >> 3;
            const int cc = (fc & 7) ^ (row & 7);     // inverse-swizzled source chunk
            const __hip_bfloat16* ga = X + (size_t)(m0 + row) * IN_F + k0 + cc * 8;
            __builtin_amdgcn_global_load_lds(
                (const __attribute__((address_space(1))) void*)ga,
                (__attribute__((address_space(3))) void*)(sA + (size_t)(c * 4 + wv) * 512),
                16, 0, 0);
            const __hip_bfloat16* gb = W + (size_t)(n0 + row) * IN_F + k0 + cc * 8;
            __builtin_amdgcn_global_load_lds(
                (const __attribute__((address_space(1))) void*)gb,
                (__attribute__((address_space(3))) void*)(sB + (size_t)(c * 4 + wv) * 512),
                16, 0, 0);
        }
        __syncthreads();

        #pragma unroll
        for (int ks = 0; ks < 2; ++ks) {
            bf16x8 af[4], bfr[4];
            #pragma unroll
            for (int i = 0; i < 4; ++i) {
                const int R = wm * 64 + i * 16 + r16;
                af[i] = *reinterpret_cast<const bf16x8*>(
                    &sA[R * 64 + ((((ks << 2) | kg) ^ (R & 7)) << 3)]);
            }
            #pragma unroll
            for (int j = 0; j < 4; ++j) {
                const int R = wn * 64 + j * 16 + r16;
                bfr[j] = *reinterpret_cast<const bf16x8*>(
                    &sB[R * 64 + ((((ks << 2) | kg) ^ (R & 7)) << 3)]);
            }
            #pragma unroll
            for (int i = 0; i < 4; ++i)
                #pragma unroll
                for (int j = 0; j < 4; ++j)
                    acc[i][j] = __builtin_amdgcn_mfma_f32_16x16x32_bf16(af[i], bfr[j], acc[i][j], 0, 0, 0);
        }
    }

    // epilogue: D[m][n], n = lane&15, m = (lane>>4)*4 + e
    #pragma unroll
    for (int i = 0; i < 4; ++i)
        #pragma unroll
        for (int j = 0; j < 4; ++j) {
            const int n = n0 + wn * 64 + j * 16 + r16;
            const float bs = bias[n];
            #pragma unroll
            for (int e = 0; e < 4; ++e) {
                const int m = m0 + wm * 64 + i * 16 + kg * 4 + e;
                out[(size_t)m * OUT_F + n] = acc[i][j][e] + bs;
            }
        }
}

extern "C" void kernel_launch(void* const* d_in, const int* in_sizes, int n_in,
                              void* d_out, int out_size, void* d_ws, size_t ws_size,
                              hipStream_t stream) {
    const float* x    = (const float*)d_in[0];
    const float* sre  = (const float*)d_in[1];
    const float* sim  = (const float*)d_in[2];
    const int*   sidx = (const int*)d_in[3];
    const float* bias = (const float*)d_in[4];
    const int nnz = in_sizes[1];
    float* out = (float*)d_out;

    char* ws = (char*)d_ws;
    // A (tiled intermediate B'): 128 MiB @ 0
    float2* A = (float2*)ws;
    // bucket arrays alias the Wb region (dead before pass 2 writes Wb)
    unsigned* packed = (unsigned*)(ws + 134217728);                       // 4*nnz
    float2* bval = (float2*)(ws + 134217728 + 4194304);                   // 8*nnz
    __hip_bfloat16* Wb = (__hip_bfloat16*)(ws + 134217728);               // 33.5 MB (pass2 out)
    __hip_bfloat16* Xb = (__hip_bfloat16*)(ws + 134217728 + 33554432);    // 16.8 MB
    char* ctl = ws + 134217728 + 33554432 + 16777216;
    unsigned* cnt   = (unsigned*)(ctl);            // 4096
    unsigned* start = (unsigned*)(ctl + 32768);    // 4097
    unsigned* pos   = (unsigned*)(ctl + 65536);    // 4096

    hipMemsetAsync(cnt, 0, 4096 * sizeof(unsigned), stream);

    const int sb = (nnz + 255) / 256;
    hist_kernel<<<sb, 256, 0, stream>>>(sidx, cnt, nnz);
    scan_kernel<<<1, 256, 0, stream>>>(cnt, start, pos);
    bucket_scatter_kernel<<<sb, 256, 0, stream>>>(sidx, sre, sim, pos, packed, bval, nnz);

    // pass 1: scatter winners into LDS + ifft along original axis 0; tiled output
    ifft_pass1_kernel<<<FFT_N, 256, 0, stream>>>(start, packed, bval, A);
    // pass 2: ifft along axis 1 via tiled column reads, real part -> bf16 weight
    ifft_pass2_kernel<<<FFT_N, 256, 0, stream>>>(A, Wb);

    cast_x_kernel<<<(MROWS * IN_F / 4 + 255) / 256, 256, 0, stream>>>(
        (const float4*)x, (ushort4*)Xb, MROWS * IN_F / 4);

    gemm_kernel<<<dim3(OUT_F / 128, MROWS / 128), 256, 0, stream>>>(Xb, Wb, bias, out);
}

// Round 7
// 297.257 us; speedup vs baseline: 1.1824x; 1.0427x over previous
//
#include <hip/hip_runtime.h>
#include <hip/hip_bf16.h>

#define OUT_F 4096
#define IN_F 4096
#define MROWS 2048            // 4*512 batch rows
#define FFT_N 4096

typedef short bf16x8 __attribute__((ext_vector_type(8)));
typedef float f32x4 __attribute__((ext_vector_type(4)));

// ================= bucket build (counting sort by column v) =================
__global__ void hist_kernel(const int* __restrict__ idx, unsigned* __restrict__ cnt, int nnz) {
    int k = blockIdx.x * blockDim.x + threadIdx.x;
    if (k < nnz) atomicAdd(&cnt[idx[k] & (IN_F - 1)], 1u);
}

__global__ void __launch_bounds__(256) scan_kernel(const unsigned* __restrict__ cnt,
                                                   unsigned* __restrict__ start,
                                                   unsigned* __restrict__ pos) {
    __shared__ unsigned part[257];
    const int t = threadIdx.x;
    unsigned s = 0;
    #pragma unroll
    for (int j = 0; j < 16; ++j) s += cnt[t * 16 + j];
    part[t + 1] = s;
    if (t == 0) part[0] = 0;
    __syncthreads();
    if (t == 0)
        for (int i = 1; i <= 256; ++i) part[i] += part[i - 1];
    __syncthreads();
    unsigned run = part[t];
    #pragma unroll
    for (int j = 0; j < 16; ++j) {
        start[t * 16 + j] = run;
        pos[t * 16 + j] = run;
        run += cnt[t * 16 + j];
    }
    if (t == 255) start[4096] = run;
}

__global__ void bucket_scatter_kernel(const int* __restrict__ idx, const float* __restrict__ re,
                                      const float* __restrict__ im, unsigned* __restrict__ pos,
                                      unsigned* __restrict__ packed, float2* __restrict__ val,
                                      int nnz) {
    int k = blockIdx.x * blockDim.x + threadIdx.x;
    if (k < nnz) {
        int id = idx[k];
        unsigned v = (unsigned)id & (IN_F - 1);
        unsigned u = (unsigned)id >> 12;
        unsigned p = atomicAdd(&pos[v], 1u);
        packed[p] = ((unsigned)k << 12) | u;   // k in high 20 bits -> max(packed) == max(k)
        val[p] = make_float2(re[k], im[k]);
    }
}

// ================= 16-pt inverse FFT building blocks =================
__device__ __forceinline__ void bflyw(float2& a, float2& b, float wr, float wi) {
    float tr = b.x * wr - b.y * wi;
    float ti = b.x * wi + b.y * wr;
    b.x = a.x - tr; b.y = a.y - ti;
    a.x += tr; a.y += ti;
}
__device__ __forceinline__ void bfly1(float2& a, float2& b) {   // w = 1
    float tr = b.x, ti = b.y;
    b.x = a.x - tr; b.y = a.y - ti;
    a.x += tr; a.y += ti;
}
__device__ __forceinline__ void bflyI(float2& a, float2& b) {   // w = +i
    float tr = -b.y, ti = b.x;
    b.x = a.x - tr; b.y = a.y - ti;
    a.x += tr; a.y += ti;
}

#define C8f  0.70710678118654752f
#define C16f 0.92387953251128676f
#define S16f 0.38268343236508977f

// inverse 16-pt FFT (+i convention). Input in bit-reversed slots, output natural.
__device__ __forceinline__ void fft16(float2 r[16]) {
    bfly1(r[0], r[1]);  bfly1(r[2], r[3]);  bfly1(r[4], r[5]);   bfly1(r[6], r[7]);
    bfly1(r[8], r[9]);  bfly1(r[10], r[11]); bfly1(r[12], r[13]); bfly1(r[14], r[15]);
    bfly1(r[0], r[2]);  bflyI(r[1], r[3]);
    bfly1(r[4], r[6]);  bflyI(r[5], r[7]);
    bfly1(r[8], r[10]); bflyI(r[9], r[11]);
    bfly1(r[12], r[14]); bflyI(r[13], r[15]);
    bfly1(r[0], r[4]);  bflyw(r[1], r[5], C8f, C8f);  bflyI(r[2], r[6]);  bflyw(r[3], r[7], -C8f, C8f);
    bfly1(r[8], r[12]); bflyw(r[9], r[13], C8f, C8f); bflyI(r[10], r[14]); bflyw(r[11], r[15], -C8f, C8f);
    bfly1(r[0], r[8]);
    bflyw(r[1], r[9],  C16f, S16f);
    bflyw(r[2], r[10], C8f,  C8f);
    bflyw(r[3], r[11], S16f, C16f);
    bflyI(r[4], r[12]);
    bflyw(r[5], r[13], -S16f, C16f);
    bflyw(r[6], r[14], -C8f,  C8f);
    bflyw(r[7], r[15], -C16f, S16f);
}

// LDS XOR swizzle: bijective on [0,4096)
__device__ __forceinline__ int swz(int a) { return a ^ ((a >> 5) & 31); }

__device__ __forceinline__ void fft4096_lds(float* bre, float* bim, int t, float2 r[16],
                                            const int* rv) {
    // ---- phase 1: 16-pt over n1, column n2 = t ----
    #pragma unroll
    for (int n1 = 0; n1 < 16; ++n1) {
        int a = swz(256 * n1 + t);
        r[rv[n1]] = make_float2(bre[a], bim[a]);
    }
    fft16(r);
    {
        float s, c;
        sincosf((float)t * 1.5339807878856412e-3f, &s, &c);   // 2*pi/4096
        float2 w = make_float2(c, s), cur = make_float2(1.f, 0.f);
        #pragma unroll
        for (int k = 0; k < 16; ++k) {
            float xr = r[k].x * cur.x - r[k].y * cur.y;
            float xi = r[k].x * cur.y + r[k].y * cur.x;
            r[k].x = xr; r[k].y = xi;
            float nr = cur.x * w.x - cur.y * w.y;
            float ni = cur.x * w.y + cur.y * w.x;
            cur.x = nr; cur.y = ni;
        }
    }
    #pragma unroll
    for (int k = 0; k < 16; ++k) {
        int a = swz(256 * k + t);
        bre[a] = r[k].x; bim[a] = r[k].y;
    }
    __syncthreads();

    // ---- phase 2 ----
    const int k1 = t >> 4;
    const int lo = t & 15;
    const int base2 = 256 * k1 + lo;
    #pragma unroll
    for (int m1 = 0; m1 < 16; ++m1) {
        int a = swz(base2 + 16 * m1);
        r[rv[m1]] = make_float2(bre[a], bim[a]);
    }
    fft16(r);
    {
        float s, c;
        sincosf((float)lo * 2.45436926061702596e-2f, &s, &c); // 2*pi/256
        float2 w = make_float2(c, s), cur = make_float2(1.f, 0.f);
        #pragma unroll
        for (int k = 0; k < 16; ++k) {
            float xr = r[k].x * cur.x - r[k].y * cur.y;
            float xi = r[k].x * cur.y + r[k].y * cur.x;
            r[k].x = xr; r[k].y = xi;
            float nr = cur.x * w.x - cur.y * w.y;
            float ni = cur.x * w.y + cur.y * w.x;
            cur.x = nr; cur.y = ni;
        }
    }
    #pragma unroll
    for (int k = 0; k < 16; ++k) {
        int a = swz(base2 + 16 * k);
        bre[a] = r[k].x; bim[a] = r[k].y;
    }
    __syncthreads();

    // ---- phase 3 ----
    const int base3 = 256 * k1 + 16 * lo;
    #pragma unroll
    for (int m = 0; m < 16; ++m) {
        int a = swz(base3 + m);
        r[rv[m]] = make_float2(bre[a], bim[a]);
    }
    fft16(r);
    __syncthreads();   // all reads done before digit-swap scatter overwrites
}

// ---------------- pass 1: bucket-scatter into LDS + 4096-pt IFFT ----------------
// Output written TILED, width 8: B'[u>>3][v][u&7] — one 64-B line holds the 8
// sibling u-columns, so pass 2 reads full lines. kwin ALIASES bre (32 KB LDS).
__global__ void __launch_bounds__(256) ifft_pass1_kernel(const unsigned* __restrict__ start,
                                                         const unsigned* __restrict__ packed,
                                                         const float2* __restrict__ val,
                                                         float2* __restrict__ outp) {
    __shared__ float bre[FFT_N];
    __shared__ float bim[FFT_N];
    unsigned* kwin = (unsigned*)bre;   // alias: dead before bre is zero-filled
    const int t = threadIdx.x;
    const int v = blockIdx.x;

    const unsigned s0 = start[v], s1 = start[v + 1];

    // load this thread's bucket entries into registers (static indices after unroll)
    unsigned pk[4]; float2 wv[4]; bool vld[4]; bool win[4];
    #pragma unroll
    for (int e = 0; e < 4; ++e) {
        unsigned i = s0 + (unsigned)t + 256u * (unsigned)e;
        vld[e] = (i < s1);
        pk[e] = vld[e] ? packed[i] : 0u;
        wv[e] = vld[e] ? val[i] : make_float2(0.f, 0.f);
    }

    // winner resolution in kwin (aliasing bre)
    for (int j = t; j < FFT_N; j += 256) kwin[j] = 0u;
    __syncthreads();
    #pragma unroll
    for (int e = 0; e < 4; ++e)
        if (vld[e]) atomicMax(&kwin[pk[e] & 4095u], pk[e]);
    __syncthreads();
    #pragma unroll
    for (int e = 0; e < 4; ++e)
        win[e] = vld[e] && (kwin[pk[e] & 4095u] == pk[e]);
    __syncthreads();   // all kwin reads done before bre overwrites it

    for (int j = t; j < FFT_N; j += 256) { bre[j] = 0.f; bim[j] = 0.f; }
    __syncthreads();
    #pragma unroll
    for (int e = 0; e < 4; ++e)
        if (win[e]) {
            int a = swz((int)(pk[e] & 4095u));
            bre[a] = wv[e].x; bim[a] = wv[e].y;   // unique u among winners -> no races
        }
    __syncthreads();

    const int rv[16] = {0, 8, 4, 12, 2, 10, 6, 14, 1, 9, 5, 13, 3, 11, 7, 15};
    float2 r[16];
    fft4096_lds(bre, bim, t, r, rv);

    const float scale = 1.0f / 4096.0f;
    const int k1 = t >> 4, lo = t & 15;
    const int outb = k1 + 16 * lo;
    #pragma unroll
    for (int j2 = 0; j2 < 16; ++j2) {
        int a = swz(outb + 256 * j2);
        bre[a] = r[j2].x * scale;
        bim[a] = r[j2].y * scale;
    }
    __syncthreads();

    // tiled write: element (v, j) -> B'[(j>>3)*4096 + v][j&7]
    // 8 lanes cover one full 64-B line; each wave writes 8 full lines
    for (int j = t; j < FFT_N; j += 256) {
        int a = swz(j);
        outp[((size_t)(j >> 3) * FFT_N + v) * 8 + (j & 7)] = make_float2(bre[a], bim[a]);
    }
}

// ---------------- pass 2: 4096-pt IFFT per column (tiled read), real -> bf16 ----------------
// Block handles output row u. Reads B'[u>>3][v][u&7]: a wave's 64 lanes read a
// CONTIGUOUS 4 KB region; the 8 blocks sharing a 256 KB panel (same u>>3) are
// co-dispatched on one XCD via u = (bid&7)*512 + (bid>>3).
__global__ void __launch_bounds__(256) ifft_pass2_kernel(const float2* __restrict__ data,
                                                         __hip_bfloat16* __restrict__ wout) {
    __shared__ float bre[FFT_N];
    __shared__ float bim[FFT_N];
    const int t = threadIdx.x;
    const int bid = blockIdx.x;
    const int u = (bid & 7) * 512 + (bid >> 3);
    const float2* __restrict__ gp = data + (size_t)(u >> 3) * FFT_N * 8 + (u & 7);

    for (int j = t; j < FFT_N; j += 256) {
        float2 v2 = gp[(size_t)j * 8];
        int a = swz(j);
        bre[a] = v2.x; bim[a] = v2.y;
    }
    __syncthreads();

    const int rv[16] = {0, 8, 4, 12, 2, 10, 6, 14, 1, 9, 5, 13, 3, 11, 7, 15};
    float2 r[16];
    fft4096_lds(bre, bim, t, r, rv);

    const float scale = 1.0f / 4096.0f;
    const int k1 = t >> 4, lo = t & 15;
    const int outb = k1 + 16 * lo;
    #pragma unroll
    for (int j2 = 0; j2 < 16; ++j2) {
        int a = swz(outb + 256 * j2);
        bre[a] = r[j2].x * scale;
    }
    __syncthreads();

    __hip_bfloat16* __restrict__ o = wout + (size_t)u * FFT_N;
    for (int j = t; j < FFT_N; j += 256) o[j] = __float2bfloat16(bre[swz(j)]);
}

// ---------------- f32 -> bf16 cast of x ----------------
__global__ void cast_x_kernel(const float4* __restrict__ x, ushort4* __restrict__ xb, int n4) {
    int i = blockIdx.x * blockDim.x + threadIdx.x;
    if (i < n4) {
        float4 v = x[i];
        __hip_bfloat16 a = __float2bfloat16(v.x);
        __hip_bfloat16 b = __float2bfloat16(v.y);
        __hip_bfloat16 c = __float2bfloat16(v.z);
        __hip_bfloat16 d = __float2bfloat16(v.w);
        ushort4 o;
        o.x = *reinterpret_cast<unsigned short*>(&a);
        o.y = *reinterpret_cast<unsigned short*>(&b);
        o.z = *reinterpret_cast<unsigned short*>(&c);
        o.w = *reinterpret_cast<unsigned short*>(&d);
        xb[i] = o;
    }
}

// ---------------- bf16 MFMA GEMM: out[M,N] = X[M,K] * W[N,K]^T + bias ----------------
// BM=128, BN=256, BK=64; 8 waves (2M x 4N), per-wave 64x64 output.
// 3-buffer LDS (144 KB), depth-2 prefetch, counted vmcnt(6) (T3+T4), setprio (T5).
// T2 swizzle: LDS chunk p of row holds logical k-chunk p ^ (row&7), applied via
// inverse-swizzled global source + swizzled ds_read (rule #21).
// Per tile: 6 global_load_lds/thread (A:2, B:4). Stage for tile t+2 issued at
// tile t; vmcnt(6) before BAR(B) certifies tile t+1 landed (6 newest = t+2's).
__device__ __forceinline__ void stage_tile(const __hip_bfloat16* __restrict__ X,
                                           const __hip_bfloat16* __restrict__ W,
                                           __hip_bfloat16* __restrict__ buf,
                                           int m0, int n0, int tt, int wv, int ln) {
    const int k0n = tt * 64;
    __hip_bfloat16* bufB = buf + 8192;
    #pragma unroll
    for (int kk = 0; kk < 2; ++kk) {
        const int s = kk * 512 + wv * 64 + ln;
        const int row = s >> 3;
        const int cc = (s & 7) ^ (row & 7);
        const __hip_bfloat16* g = X + (size_t)(m0 + row) * IN_F + k0n + cc * 8;
        __builtin_amdgcn_global_load_lds(
            (const __attribute__((address_space(1))) void*)g,
            (__attribute__((address_space(3))) void*)(buf + (size_t)(kk * 512 + wv * 64) * 8),
            16, 0, 0);
    }
    #pragma unroll
    for (int u = 0; u < 2; ++u)
        #pragma unroll
        for (int kk = 0; kk < 2; ++kk) {
            const int s = kk * 512 + wv * 64 + ln;
            const int row = u * 128 + (s >> 3);
            const int cc = (s & 7) ^ (row & 7);
            const __hip_bfloat16* g = W + (size_t)(n0 + row) * IN_F + k0n + cc * 8;
            __builtin_amdgcn_global_load_lds(
                (const __attribute__((address_space(1))) void*)g,
                (__attribute__((address_space(3))) void*)(bufB + (size_t)(u * 1024 + kk * 512 + wv * 64) * 8),
                16, 0, 0);
        }
}

__global__ void __launch_bounds__(512, 2) gemm_kernel(const __hip_bfloat16* __restrict__ X,
                                                      const __hip_bfloat16* __restrict__ W,
                                                      const float* __restrict__ bias,
                                                      float* __restrict__ out) {
    __shared__ __align__(16) __hip_bfloat16 smem[3 * 24576];   // 144 KB
    const int tid = threadIdx.x;
    const int wv = tid >> 6;        // wave 0..7
    const int ln = tid & 63;
    const int m0 = blockIdx.y * 128;
    const int n0 = blockIdx.x * 256;
    const int wm = wv >> 2, wn = wv & 3;
    const int r16 = ln & 15, kg = ln >> 4;
    const int x7 = ln & 7;

    f32x4 acc[4][4];
    #pragma unroll
    for (int i = 0; i < 4; ++i)
        #pragma unroll
        for (int j = 0; j < 4; ++j) acc[i][j] = (f32x4){0.f, 0.f, 0.f, 0.f};

    // prologue: prefetch tiles 0 and 1
    stage_tile(X, W, smem, m0, n0, 0, wv, ln);
    stage_tile(X, W, smem + 24576, m0, n0, 1, wv, ln);
    asm volatile("s_waitcnt vmcnt(6)" ::: "memory");   // tile 0 landed
    __builtin_amdgcn_s_barrier();

    for (int t = 0; t < 64; ++t) {
        const __hip_bfloat16* Ab = smem + (t % 3) * 24576;
        const __hip_bfloat16* Bb = Ab + 8192;

        // phase A: all 16 fragment reads + issue prefetch for tile t+2
        bf16x8 a0[4], a1[4], b0[4], b1[4];
        #pragma unroll
        for (int i = 0; i < 4; ++i) {
            const int R = wm * 64 + i * 16 + r16;
            a0[i] = *reinterpret_cast<const bf16x8*>(Ab + R * 64 + ((kg ^ x7) << 3));
            a1[i] = *reinterpret_cast<const bf16x8*>(Ab + R * 64 + (((4 | kg) ^ x7) << 3));
        }
        #pragma unroll
        for (int j = 0; j < 4; ++j) {
            const int R = wn * 64 + j * 16 + r16;
            b0[j] = *reinterpret_cast<const bf16x8*>(Bb + R * 64 + ((kg ^ x7) << 3));
            b1[j] = *reinterpret_cast<const bf16x8*>(Bb + R * 64 + (((4 | kg) ^ x7) << 3));
        }
        if (t < 62)
            stage_tile(X, W, smem + ((t + 2) % 3) * 24576, m0, n0, t + 2, wv, ln);

        __builtin_amdgcn_s_barrier();                          // BAR(A)
        asm volatile("s_waitcnt lgkmcnt(0)" ::: "memory");
        __builtin_amdgcn_sched_barrier(0);
        __builtin_amdgcn_s_setprio(1);
        #pragma unroll
        for (int i = 0; i < 4; ++i)
            #pragma unroll
            for (int j = 0; j < 4; ++j)
                acc[i][j] = __builtin_amdgcn_mfma_f32_16x16x32_bf16(a0[i], b0[j], acc[i][j], 0, 0, 0);
        __builtin_amdgcn_s_setprio(0);

        // counted wait: tile t+1 landed (6 newest in flight = tile t+2's)
        if (t < 62) {
            asm volatile("s_waitcnt vmcnt(6)" ::: "memory");
        } else if (t == 62) {
            asm volatile("s_waitcnt vmcnt(0)" ::: "memory");
        }
        __builtin_amdgcn_s_barrier();                          // BAR(B)

        __builtin_amdgcn_s_setprio(1);
        #pragma unroll
        for (int i = 0; i < 4; ++i)
            #pragma unroll
            for (int j = 0; j < 4; ++j)
                acc[i][j] = __builtin_amdgcn_mfma_f32_16x16x32_bf16(a1[i], b1[j], acc[i][j], 0, 0, 0);
        __builtin_amdgcn_s_setprio(0);
    }

    // epilogue: D[m][n], n = lane&15, m = (lane>>4)*4 + e
    #pragma unroll
    for (int i = 0; i < 4; ++i)
        #pragma unroll
        for (int j = 0; j < 4; ++j) {
            const int n = n0 + wn * 64 + j * 16 + r16;
            const float bs = bias[n];
            #pragma unroll
            for (int e = 0; e < 4; ++e) {
                const int m = m0 + wm * 64 + i * 16 + kg * 4 + e;
                out[(size_t)m * OUT_F + n] = acc[i][j][e] + bs;
            }
        }
}

extern "C" void kernel_launch(void* const* d_in, const int* in_sizes, int n_in,
                              void* d_out, int out_size, void* d_ws, size_t ws_size,
                              hipStream_t stream) {
    const float* x    = (const float*)d_in[0];
    const float* sre  = (const float*)d_in[1];
    const float* sim  = (const float*)d_in[2];
    const int*   sidx = (const int*)d_in[3];
    const float* bias = (const float*)d_in[4];
    const int nnz = in_sizes[1];
    float* out = (float*)d_out;

    char* ws = (char*)d_ws;
    // A (tiled intermediate B'): 128 MiB @ 0
    float2* A = (float2*)ws;
    // bucket arrays alias the Wb region (dead before pass 2 writes Wb)
    unsigned* packed = (unsigned*)(ws + 134217728);                       // 4*nnz
    float2* bval = (float2*)(ws + 134217728 + 4194304);                   // 8*nnz
    __hip_bfloat16* Wb = (__hip_bfloat16*)(ws + 134217728);               // 33.5 MB (pass2 out)
    __hip_bfloat16* Xb = (__hip_bfloat16*)(ws + 134217728 + 33554432);    // 16.8 MB
    char* ctl = ws + 134217728 + 33554432 + 16777216;
    unsigned* cnt   = (unsigned*)(ctl);            // 4096
    unsigned* start = (unsigned*)(ctl + 32768);    // 4097
    unsigned* pos   = (unsigned*)(ctl + 65536);    // 4096

    hipMemsetAsync(cnt, 0, 4096 * sizeof(unsigned), stream);

    const int sb = (nnz + 255) / 256;
    hist_kernel<<<sb, 256, 0, stream>>>(sidx, cnt, nnz);
    scan_kernel<<<1, 256, 0, stream>>>(cnt, start, pos);
    bucket_scatter_kernel<<<sb, 256, 0, stream>>>(sidx, sre, sim, pos, packed, bval, nnz);

    // pass 1: scatter winners into LDS + ifft along original axis 0; tiled output
    ifft_pass1_kernel<<<FFT_N, 256, 0, stream>>>(start, packed, bval, A);
    // pass 2: ifft along axis 1 via tiled column reads, real part -> bf16 weight
    ifft_pass2_kernel<<<FFT_N, 256, 0, stream>>>(A, Wb);

    cast_x_kernel<<<(MROWS * IN_F / 4 + 255) / 256, 256, 0, stream>>>(
        (const float4*)x, (ushort4*)Xb, MROWS * IN_F / 4);

    gemm_kernel<<<dim3(OUT_F / 256, MROWS / 128), 512, 0, stream>>>(Xb, Wb, bias, out);
}

// Round 8
// 262.296 us; speedup vs baseline: 1.3400x; 1.1333x over previous
//
#include <hip/hip_runtime.h>
#include <hip/hip_bf16.h>

#define OUT_F 4096
#define IN_F 4096
#define MROWS 2048            // 4*512 batch rows
#define FFT_N 4096
#define HCOLS 2049            // Hermitian-reduced column count

typedef short bf16x8 __attribute__((ext_vector_type(8)));
typedef float f32x4 __attribute__((ext_vector_type(4)));

// ================= bucket build (counting sort by column v) =================
__global__ void hist_kernel(const int* __restrict__ idx, unsigned* __restrict__ cnt, int nnz) {
    int k = blockIdx.x * blockDim.x + threadIdx.x;
    if (k < nnz) atomicAdd(&cnt[idx[k] & (IN_F - 1)], 1u);
}

__global__ void __launch_bounds__(256) scan_kernel(const unsigned* __restrict__ cnt,
                                                   unsigned* __restrict__ start,
                                                   unsigned* __restrict__ pos) {
    __shared__ unsigned part[257];
    const int t = threadIdx.x;
    unsigned s = 0;
    #pragma unroll
    for (int j = 0; j < 16; ++j) s += cnt[t * 16 + j];
    part[t + 1] = s;
    if (t == 0) part[0] = 0;
    __syncthreads();
    if (t == 0)
        for (int i = 1; i <= 256; ++i) part[i] += part[i - 1];
    __syncthreads();
    unsigned run = part[t];
    #pragma unroll
    for (int j = 0; j < 16; ++j) {
        start[t * 16 + j] = run;
        pos[t * 16 + j] = run;
        run += cnt[t * 16 + j];
    }
    if (t == 255) start[4096] = run;
}

__global__ void bucket_scatter_kernel(const int* __restrict__ idx, const float* __restrict__ re,
                                      const float* __restrict__ im, unsigned* __restrict__ pos,
                                      unsigned* __restrict__ packed, float2* __restrict__ val,
                                      int nnz) {
    int k = blockIdx.x * blockDim.x + threadIdx.x;
    if (k < nnz) {
        int id = idx[k];
        unsigned v = (unsigned)id & (IN_F - 1);
        unsigned u = (unsigned)id >> 12;
        unsigned p = atomicAdd(&pos[v], 1u);
        packed[p] = ((unsigned)k << 12) | u;   // k in high 20 bits -> max(packed) == max(k)
        val[p] = make_float2(re[k], im[k]);
    }
}

// ================= 16-pt inverse FFT building blocks =================
__device__ __forceinline__ void bflyw(float2& a, float2& b, float wr, float wi) {
    float tr = b.x * wr - b.y * wi;
    float ti = b.x * wi + b.y * wr;
    b.x = a.x - tr; b.y = a.y - ti;
    a.x += tr; a.y += ti;
}
__device__ __forceinline__ void bfly1(float2& a, float2& b) {   // w = 1
    float tr = b.x, ti = b.y;
    b.x = a.x - tr; b.y = a.y - ti;
    a.x += tr; a.y += ti;
}
__device__ __forceinline__ void bflyI(float2& a, float2& b) {   // w = +i
    float tr = -b.y, ti = b.x;
    b.x = a.x - tr; b.y = a.y - ti;
    a.x += tr; a.y += ti;
}

#define C8f  0.70710678118654752f
#define C16f 0.92387953251128676f
#define S16f 0.38268343236508977f

// inverse 16-pt FFT (+i convention). Input in bit-reversed slots, output natural.
__device__ __forceinline__ void fft16(float2 r[16]) {
    bfly1(r[0], r[1]);  bfly1(r[2], r[3]);  bfly1(r[4], r[5]);   bfly1(r[6], r[7]);
    bfly1(r[8], r[9]);  bfly1(r[10], r[11]); bfly1(r[12], r[13]); bfly1(r[14], r[15]);
    bfly1(r[0], r[2]);  bflyI(r[1], r[3]);
    bfly1(r[4], r[6]);  bflyI(r[5], r[7]);
    bfly1(r[8], r[10]); bflyI(r[9], r[11]);
    bfly1(r[12], r[14]); bflyI(r[13], r[15]);
    bfly1(r[0], r[4]);  bflyw(r[1], r[5], C8f, C8f);  bflyI(r[2], r[6]);  bflyw(r[3], r[7], -C8f, C8f);
    bfly1(r[8], r[12]); bflyw(r[9], r[13], C8f, C8f); bflyI(r[10], r[14]); bflyw(r[11], r[15], -C8f, C8f);
    bfly1(r[0], r[8]);
    bflyw(r[1], r[9],  C16f, S16f);
    bflyw(r[2], r[10], C8f,  C8f);
    bflyw(r[3], r[11], S16f, C16f);
    bflyI(r[4], r[12]);
    bflyw(r[5], r[13], -S16f, C16f);
    bflyw(r[6], r[14], -C8f,  C8f);
    bflyw(r[7], r[15], -C16f, S16f);
}

// LDS XOR swizzle: bijective on [0,4096)
__device__ __forceinline__ int swz(int a) { return a ^ ((a >> 5) & 31); }

__device__ __forceinline__ void fft4096_lds(float* bre, float* bim, int t, float2 r[16],
                                            const int* rv) {
    // ---- phase 1: 16-pt over n1, column n2 = t ----
    #pragma unroll
    for (int n1 = 0; n1 < 16; ++n1) {
        int a = swz(256 * n1 + t);
        r[rv[n1]] = make_float2(bre[a], bim[a]);
    }
    fft16(r);
    {
        float s, c;
        sincosf((float)t * 1.5339807878856412e-3f, &s, &c);   // 2*pi/4096
        float2 w = make_float2(c, s), cur = make_float2(1.f, 0.f);
        #pragma unroll
        for (int k = 0; k < 16; ++k) {
            float xr = r[k].x * cur.x - r[k].y * cur.y;
            float xi = r[k].x * cur.y + r[k].y * cur.x;
            r[k].x = xr; r[k].y = xi;
            float nr = cur.x * w.x - cur.y * w.y;
            float ni = cur.x * w.y + cur.y * w.x;
            cur.x = nr; cur.y = ni;
        }
    }
    #pragma unroll
    for (int k = 0; k < 16; ++k) {
        int a = swz(256 * k + t);
        bre[a] = r[k].x; bim[a] = r[k].y;
    }
    __syncthreads();

    // ---- phase 2 ----
    const int k1 = t >> 4;
    const int lo = t & 15;
    const int base2 = 256 * k1 + lo;
    #pragma unroll
    for (int m1 = 0; m1 < 16; ++m1) {
        int a = swz(base2 + 16 * m1);
        r[rv[m1]] = make_float2(bre[a], bim[a]);
    }
    fft16(r);
    {
        float s, c;
        sincosf((float)lo * 2.45436926061702596e-2f, &s, &c); // 2*pi/256
        float2 w = make_float2(c, s), cur = make_float2(1.f, 0.f);
        #pragma unroll
        for (int k = 0; k < 16; ++k) {
            float xr = r[k].x * cur.x - r[k].y * cur.y;
            float xi = r[k].x * cur.y + r[k].y * cur.x;
            r[k].x = xr; r[k].y = xi;
            float nr = cur.x * w.x - cur.y * w.y;
            float ni = cur.x * w.y + cur.y * w.x;
            cur.x = nr; cur.y = ni;
        }
    }
    #pragma unroll
    for (int k = 0; k < 16; ++k) {
        int a = swz(base2 + 16 * k);
        bre[a] = r[k].x; bim[a] = r[k].y;
    }
    __syncthreads();

    // ---- phase 3 ----
    const int base3 = 256 * k1 + 16 * lo;
    #pragma unroll
    for (int m = 0; m < 16; ++m) {
        int a = swz(base3 + m);
        r[rv[m]] = make_float2(bre[a], bim[a]);
    }
    fft16(r);
    __syncthreads();   // all reads done before digit-swap scatter overwrites
}

// ---------------- pass 1: Hermitian-symmetrized scatter + 4096-pt IFFT over u ----------------
// Block vp in [0,2048] builds Sh(u, vp) = 0.5*D(u,vp) + 0.5*conj(D(-u,-vp)) in LDS
// (winner-resolved per original bucket), then IFFT over u -> B(o, vp).
// Output TILED width 8: B'[o>>3][vp][o&7]. kwin ALIASES bre (32 KB LDS).
__global__ void __launch_bounds__(256) ifft_pass1_kernel(const unsigned* __restrict__ start,
                                                         const unsigned* __restrict__ packed,
                                                         const float2* __restrict__ val,
                                                         float2* __restrict__ outp) {
    __shared__ float bre[FFT_N];
    __shared__ float bim[FFT_N];
    unsigned* kwin = (unsigned*)bre;   // alias: dead before bre is zero-filled
    const int t = threadIdx.x;
    const int vp = blockIdx.x;                 // 0..2048
    const int bd = vp;
    const int bm = (4096 - vp) & 4095;         // mirror bucket (== bd for vp=0,2048)
    const bool sameb = (bm == bd);

    const unsigned s0d = start[bd], s1d = start[bd + 1];
    const unsigned s0m = start[bm], s1m = start[bm + 1];

    unsigned pkD[4], pkM[4]; float2 wvD[4], wvM[4];
    bool vldD[4], vldM[4], winD[4], winM[4];
    #pragma unroll
    for (int e = 0; e < 4; ++e) {
        unsigned i = s0d + (unsigned)t + 256u * (unsigned)e;
        vldD[e] = (i < s1d);
        pkD[e] = vldD[e] ? packed[i] : 0u;
        wvD[e] = vldD[e] ? val[i] : make_float2(0.f, 0.f);
        unsigned i2 = s0m + (unsigned)t + 256u * (unsigned)e;
        vldM[e] = (i2 < s1m);
        pkM[e] = vldM[e] ? packed[i2] : 0u;
        wvM[e] = vldM[e] ? val[i2] : make_float2(0.f, 0.f);
    }

    // winner resolution, bucket D
    for (int j = t; j < FFT_N; j += 256) kwin[j] = 0u;
    __syncthreads();
    #pragma unroll
    for (int e = 0; e < 4; ++e)
        if (vldD[e]) atomicMax(&kwin[pkD[e] & 4095u], pkD[e]);
    __syncthreads();
    #pragma unroll
    for (int e = 0; e < 4; ++e)
        winD[e] = vldD[e] && (kwin[pkD[e] & 4095u] == pkD[e]);
    if (sameb) {
        #pragma unroll
        for (int e = 0; e < 4; ++e)
            winM[e] = vldM[e] && (kwin[pkM[e] & 4095u] == pkM[e]);
    }
    __syncthreads();   // all kwin reads done

    if (!sameb) {      // winner resolution, bucket M
        for (int j = t; j < FFT_N; j += 256) kwin[j] = 0u;
        __syncthreads();
        #pragma unroll
        for (int e = 0; e < 4; ++e)
            if (vldM[e]) atomicMax(&kwin[pkM[e] & 4095u], pkM[e]);
        __syncthreads();
        #pragma unroll
        for (int e = 0; e < 4; ++e)
            winM[e] = vldM[e] && (kwin[pkM[e] & 4095u] == pkM[e]);
        __syncthreads();
    }

    for (int j = t; j < FFT_N; j += 256) { bre[j] = 0.f; bim[j] = 0.f; }
    __syncthreads();
    // direct scatter: +0.5 * D(u, vp) at u  (winner positions unique)
    #pragma unroll
    for (int e = 0; e < 4; ++e)
        if (winD[e]) {
            int a = swz((int)(pkD[e] & 4095u));
            bre[a] = 0.5f * wvD[e].x; bim[a] = 0.5f * wvD[e].y;
        }
    __syncthreads();
    // mirror scatter: +0.5 * conj(D(u2, -vp)) at (4096-u2)  (RMW; unique positions)
    #pragma unroll
    for (int e = 0; e < 4; ++e)
        if (winM[e]) {
            int u2 = (int)(pkM[e] & 4095u);
            int a = swz((4096 - u2) & 4095);
            bre[a] += 0.5f * wvM[e].x; bim[a] -= 0.5f * wvM[e].y;
        }
    __syncthreads();

    const int rv[16] = {0, 8, 4, 12, 2, 10, 6, 14, 1, 9, 5, 13, 3, 11, 7, 15};
    float2 r[16];
    fft4096_lds(bre, bim, t, r, rv);

    const float scale = 1.0f / 4096.0f;
    const int k1 = t >> 4, lo = t & 15;
    const int outb = k1 + 16 * lo;
    #pragma unroll
    for (int j2 = 0; j2 < 16; ++j2) {
        int a = swz(outb + 256 * j2);
        bre[a] = r[j2].x * scale;
        bim[a] = r[j2].y * scale;
    }
    __syncthreads();

    // tiled write: element (o=j, vp) -> B'[(j>>3)*HCOLS + vp][j&7]
    for (int j = t; j < FFT_N; j += 256) {
        int a = swz(j);
        outp[((size_t)(j >> 3) * HCOLS + vp) * 8 + (j & 7)] = make_float2(bre[a], bim[a]);
    }
}

// ---------------- pass 2: c2r IFFT over v, TWO output rows per block ----------------
// Block handles rows o1=2s, o2=2s+1. Z(v) = H(o1,v) + i*H(o2,v) for v<=2048,
// Z(4096-v) = conj(H(o1,v)) + i*conj(H(o2,v)). IFFT -> w[o1]=Re, w[o2]=Im.
// o1&7 even -> (H1,H2) pair is one aligned float4 in the width-8 panel.
__global__ void __launch_bounds__(256) ifft_pass2_kernel(const float2* __restrict__ data,
                                                         __hip_bfloat16* __restrict__ wout) {
    __shared__ float bre[FFT_N];
    __shared__ float bim[FFT_N];
    const int t = threadIdx.x;
    const int bid = blockIdx.x;                       // 0..2047
    const int s = (bid & 7) * 256 + (bid >> 3);       // XCD-chunked
    const int o1 = 2 * s;
    const float4* __restrict__ gp = (const float4*)
        (data + (size_t)(o1 >> 3) * HCOLS * 8 + (o1 & 7));

    for (int j = t; j < HCOLS; j += 256) {
        float4 h = gp[(size_t)j * 4];                 // h.xy=H1(j), h.zw=H2(j)
        int a = swz(j & 4095);
        bre[a] = h.x - h.w; bim[a] = h.y + h.z;       // Z(j) = H1 + i*H2
        if (j != 0 && j != 2048) {
            int a2 = swz(4096 - j);                   // Z(-j) = conj(H1) + i*conj(H2)
            bre[a2] = h.x + h.w; bim[a2] = h.z - h.y;
        }
    }
    __syncthreads();

    const int rv[16] = {0, 8, 4, 12, 2, 10, 6, 14, 1, 9, 5, 13, 3, 11, 7, 15};
    float2 r[16];
    fft4096_lds(bre, bim, t, r, rv);

    const float scale = 1.0f / 4096.0f;
    const int k1 = t >> 4, lo = t & 15;
    const int outb = k1 + 16 * lo;
    #pragma unroll
    for (int j2 = 0; j2 < 16; ++j2) {
        int a = swz(outb + 256 * j2);
        bre[a] = r[j2].x * scale;                     // w[o1]
        bim[a] = r[j2].y * scale;                     // w[o2]
    }
    __syncthreads();

    __hip_bfloat16* __restrict__ out1 = wout + (size_t)o1 * FFT_N;
    __hip_bfloat16* __restrict__ out2 = wout + (size_t)(o1 + 1) * FFT_N;
    for (int j = t; j < FFT_N; j += 256) {
        int a = swz(j);
        out1[j] = __float2bfloat16(bre[a]);
        out2[j] = __float2bfloat16(bim[a]);
    }
}

// ---------------- f32 -> bf16 cast of x ----------------
__global__ void cast_x_kernel(const float4* __restrict__ x, ushort4* __restrict__ xb, int n4) {
    int i = blockIdx.x * blockDim.x + threadIdx.x;
    if (i < n4) {
        float4 v = x[i];
        __hip_bfloat16 a = __float2bfloat16(v.x);
        __hip_bfloat16 b = __float2bfloat16(v.y);
        __hip_bfloat16 c = __float2bfloat16(v.z);
        __hip_bfloat16 d = __float2bfloat16(v.w);
        ushort4 o;
        o.x = *reinterpret_cast<unsigned short*>(&a);
        o.y = *reinterpret_cast<unsigned short*>(&b);
        o.z = *reinterpret_cast<unsigned short*>(&c);
        o.w = *reinterpret_cast<unsigned short*>(&d);
        xb[i] = o;
    }
}

// ---------------- bf16 MFMA GEMM (unchanged from R7) ----------------
__device__ __forceinline__ void stage_tile(const __hip_bfloat16* __restrict__ X,
                                           const __hip_bfloat16* __restrict__ W,
                                           __hip_bfloat16* __restrict__ buf,
                                           int m0, int n0, int tt, int wv, int ln) {
    const int k0n = tt * 64;
    __hip_bfloat16* bufB = buf + 8192;
    #pragma unroll
    for (int kk = 0; kk < 2; ++kk) {
        const int s = kk * 512 + wv * 64 + ln;
        const int row = s >> 3;
        const int cc = (s & 7) ^ (row & 7);
        const __hip_bfloat16* g = X + (size_t)(m0 + row) * IN_F + k0n + cc * 8;
        __builtin_amdgcn_global_load_lds(
            (const __attribute__((address_space(1))) void*)g,
            (__attribute__((address_space(3))) void*)(buf + (size_t)(kk * 512 + wv * 64) * 8),
            16, 0, 0);
    }
    #pragma unroll
    for (int u = 0; u < 2; ++u)
        #pragma unroll
        for (int kk = 0; kk < 2; ++kk) {
            const int s = kk * 512 + wv * 64 + ln;
            const int row = u * 128 + (s >> 3);
            const int cc = (s & 7) ^ (row & 7);
            const __hip_bfloat16* g = W + (size_t)(n0 + row) * IN_F + k0n + cc * 8;
            __builtin_amdgcn_global_load_lds(
                (const __attribute__((address_space(1))) void*)g,
                (__attribute__((address_space(3))) void*)(bufB + (size_t)(u * 1024 + kk * 512 + wv * 64) * 8),
                16, 0, 0);
        }
}

__global__ void __launch_bounds__(512, 2) gemm_kernel(const __hip_bfloat16* __restrict__ X,
                                                      const __hip_bfloat16* __restrict__ W,
                                                      const float* __restrict__ bias,
                                                      float* __restrict__ out) {
    __shared__ __align__(16) __hip_bfloat16 smem[3 * 24576];   // 144 KB
    const int tid = threadIdx.x;
    const int wv = tid >> 6;        // wave 0..7
    const int ln = tid & 63;
    const int m0 = blockIdx.y * 128;
    const int n0 = blockIdx.x * 256;
    const int wm = wv >> 2, wn = wv & 3;
    const int r16 = ln & 15, kg = ln >> 4;
    const int x7 = ln & 7;

    f32x4 acc[4][4];
    #pragma unroll
    for (int i = 0; i < 4; ++i)
        #pragma unroll
        for (int j = 0; j < 4; ++j) acc[i][j] = (f32x4){0.f, 0.f, 0.f, 0.f};

    stage_tile(X, W, smem, m0, n0, 0, wv, ln);
    stage_tile(X, W, smem + 24576, m0, n0, 1, wv, ln);
    asm volatile("s_waitcnt vmcnt(6)" ::: "memory");   // tile 0 landed
    __builtin_amdgcn_s_barrier();

    for (int t = 0; t < 64; ++t) {
        const __hip_bfloat16* Ab = smem + (t % 3) * 24576;
        const __hip_bfloat16* Bb = Ab + 8192;

        bf16x8 a0[4], a1[4], b0[4], b1[4];
        #pragma unroll
        for (int i = 0; i < 4; ++i) {
            const int R = wm * 64 + i * 16 + r16;
            a0[i] = *reinterpret_cast<const bf16x8*>(Ab + R * 64 + ((kg ^ x7) << 3));
            a1[i] = *reinterpret_cast<const bf16x8*>(Ab + R * 64 + (((4 | kg) ^ x7) << 3));
        }
        #pragma unroll
        for (int j = 0; j < 4; ++j) {
            const int R = wn * 64 + j * 16 + r16;
            b0[j] = *reinterpret_cast<const bf16x8*>(Bb + R * 64 + ((kg ^ x7) << 3));
            b1[j] = *reinterpret_cast<const bf16x8*>(Bb + R * 64 + (((4 | kg) ^ x7) << 3));
        }
        if (t < 62)
            stage_tile(X, W, smem + ((t + 2) % 3) * 24576, m0, n0, t + 2, wv, ln);

        __builtin_amdgcn_s_barrier();                          // BAR(A)
        asm volatile("s_waitcnt lgkmcnt(0)" ::: "memory");
        __builtin_amdgcn_sched_barrier(0);
        __builtin_amdgcn_s_setprio(1);
        #pragma unroll
        for (int i = 0; i < 4; ++i)
            #pragma unroll
            for (int j = 0; j < 4; ++j)
                acc[i][j] = __builtin_amdgcn_mfma_f32_16x16x32_bf16(a0[i], b0[j], acc[i][j], 0, 0, 0);
        __builtin_amdgcn_s_setprio(0);

        if (t < 62) {
            asm volatile("s_waitcnt vmcnt(6)" ::: "memory");
        } else if (t == 62) {
            asm volatile("s_waitcnt vmcnt(0)" ::: "memory");
        }
        __builtin_amdgcn_s_barrier();                          // BAR(B)

        __builtin_amdgcn_s_setprio(1);
        #pragma unroll
        for (int i = 0; i < 4; ++i)
            #pragma unroll
            for (int j = 0; j < 4; ++j)
                acc[i][j] = __builtin_amdgcn_mfma_f32_16x16x32_bf16(a1[i], b1[j], acc[i][j], 0, 0, 0);
        __builtin_amdgcn_s_setprio(0);
    }

    #pragma unroll
    for (int i = 0; i < 4; ++i)
        #pragma unroll
        for (int j = 0; j < 4; ++j) {
            const int n = n0 + wn * 64 + j * 16 + r16;
            const float bs = bias[n];
            #pragma unroll
            for (int e = 0; e < 4; ++e) {
                const int m = m0 + wm * 64 + i * 16 + kg * 4 + e;
                out[(size_t)m * OUT_F + n] = acc[i][j][e] + bs;
            }
        }
}

extern "C" void kernel_launch(void* const* d_in, const int* in_sizes, int n_in,
                              void* d_out, int out_size, void* d_ws, size_t ws_size,
                              hipStream_t stream) {
    const float* x    = (const float*)d_in[0];
    const float* sre  = (const float*)d_in[1];
    const float* sim  = (const float*)d_in[2];
    const int*   sidx = (const int*)d_in[3];
    const float* bias = (const float*)d_in[4];
    const int nnz = in_sizes[1];
    float* out = (float*)d_out;

    char* ws = (char*)d_ws;
    // A (tiled intermediate B', 4096 x 2049 complex = 67.1 MB) @ 0
    float2* A = (float2*)ws;
    // bucket arrays alias the Wb region (dead before pass 2 writes Wb)
    unsigned* packed = (unsigned*)(ws + 134217728);                       // 4*nnz
    float2* bval = (float2*)(ws + 134217728 + 4194304);                   // 8*nnz
    __hip_bfloat16* Wb = (__hip_bfloat16*)(ws + 134217728);               // 33.5 MB (pass2 out)
    __hip_bfloat16* Xb = (__hip_bfloat16*)(ws + 134217728 + 33554432);    // 16.8 MB
    char* ctl = ws + 134217728 + 33554432 + 16777216;
    unsigned* cnt   = (unsigned*)(ctl);            // 4096
    unsigned* start = (unsigned*)(ctl + 32768);    // 4097
    unsigned* pos   = (unsigned*)(ctl + 65536);    // 4096

    hipMemsetAsync(cnt, 0, 4096 * sizeof(unsigned), stream);

    const int sb = (nnz + 255) / 256;
    hist_kernel<<<sb, 256, 0, stream>>>(sidx, cnt, nnz);
    scan_kernel<<<1, 256, 0, stream>>>(cnt, start, pos);
    bucket_scatter_kernel<<<sb, 256, 0, stream>>>(sidx, sre, sim, pos, packed, bval, nnz);

    // pass 1: Hermitian-symmetrized scatter + IFFT over u; columns 0..2048 only
    ifft_pass1_kernel<<<HCOLS, 256, 0, stream>>>(start, packed, bval, A);
    // pass 2: c2r IFFT over v, two rows per block -> bf16 weight
    ifft_pass2_kernel<<<FFT_N / 2, 256, 0, stream>>>(A, Wb);

    cast_x_kernel<<<(MROWS * IN_F / 4 + 255) / 256, 256, 0, stream>>>(
        (const float4*)x, (ushort4*)Xb, MROWS * IN_F / 4);

    gemm_kernel<<<dim3(OUT_F / 256, MROWS / 128), 512, 0, stream>>>(Xb, Wb, bias, out);
}

// Round 9
// 253.518 us; speedup vs baseline: 1.3864x; 1.0346x over previous
//
#include <hip/hip_runtime.h>
#include <hip/hip_bf16.h>

#define OUT_F 4096
#define IN_F 4096
#define MROWS 2048            // 4*512 batch rows
#define FFT_N 4096
#define HCOLS 2049            // Hermitian-reduced column count

typedef short bf16x8 __attribute__((ext_vector_type(8)));
typedef float f32x4 __attribute__((ext_vector_type(4)));

// ================= bucket build (counting sort by column v) =================
__global__ void hist_kernel(const int* __restrict__ idx, unsigned* __restrict__ cnt, int nnz) {
    int k = blockIdx.x * blockDim.x + threadIdx.x;
    if (k < nnz) atomicAdd(&cnt[idx[k] & (IN_F - 1)], 1u);
}

__global__ void __launch_bounds__(256) scan_kernel(const unsigned* __restrict__ cnt,
                                                   unsigned* __restrict__ start,
                                                   unsigned* __restrict__ pos) {
    __shared__ unsigned part[256];
    const int t = threadIdx.x;
    unsigned s = 0;
    #pragma unroll
    for (int j = 0; j < 16; ++j) s += cnt[t * 16 + j];
    part[t] = s;
    __syncthreads();
    // Kogge-Stone inclusive prefix over 256 partials
    #pragma unroll
    for (int off = 1; off < 256; off <<= 1) {
        unsigned add = (t >= off) ? part[t - off] : 0u;
        __syncthreads();
        part[t] += add;
        __syncthreads();
    }
    unsigned run = part[t] - s;   // exclusive prefix
    #pragma unroll
    for (int j = 0; j < 16; ++j) {
        start[t * 16 + j] = run;
        pos[t * 16 + j] = run;
        run += cnt[t * 16 + j];
    }
    if (t == 255) start[4096] = part[255];
}

__global__ void bucket_scatter_kernel(const int* __restrict__ idx, const float* __restrict__ re,
                                      const float* __restrict__ im, unsigned* __restrict__ pos,
                                      unsigned* __restrict__ packed, float2* __restrict__ val,
                                      int nnz) {
    int k = blockIdx.x * blockDim.x + threadIdx.x;
    if (k < nnz) {
        int id = idx[k];
        unsigned v = (unsigned)id & (IN_F - 1);
        unsigned u = (unsigned)id >> 12;
        unsigned p = atomicAdd(&pos[v], 1u);
        packed[p] = ((unsigned)k << 12) | u;   // k in high 20 bits -> max(packed) == max(k)
        val[p] = make_float2(re[k], im[k]);
    }
}

// ================= 16-pt inverse FFT building blocks =================
__device__ __forceinline__ void bflyw(float2& a, float2& b, float wr, float wi) {
    float tr = b.x * wr - b.y * wi;
    float ti = b.x * wi + b.y * wr;
    b.x = a.x - tr; b.y = a.y - ti;
    a.x += tr; a.y += ti;
}
__device__ __forceinline__ void bfly1(float2& a, float2& b) {   // w = 1
    float tr = b.x, ti = b.y;
    b.x = a.x - tr; b.y = a.y - ti;
    a.x += tr; a.y += ti;
}
__device__ __forceinline__ void bflyI(float2& a, float2& b) {   // w = +i
    float tr = -b.y, ti = b.x;
    b.x = a.x - tr; b.y = a.y - ti;
    a.x += tr; a.y += ti;
}

#define C8f  0.70710678118654752f
#define C16f 0.92387953251128676f
#define S16f 0.38268343236508977f

// inverse 16-pt FFT (+i convention). Input in bit-reversed slots, output natural.
__device__ __forceinline__ void fft16(float2 r[16]) {
    bfly1(r[0], r[1]);  bfly1(r[2], r[3]);  bfly1(r[4], r[5]);   bfly1(r[6], r[7]);
    bfly1(r[8], r[9]);  bfly1(r[10], r[11]); bfly1(r[12], r[13]); bfly1(r[14], r[15]);
    bfly1(r[0], r[2]);  bflyI(r[1], r[3]);
    bfly1(r[4], r[6]);  bflyI(r[5], r[7]);
    bfly1(r[8], r[10]); bflyI(r[9], r[11]);
    bfly1(r[12], r[14]); bflyI(r[13], r[15]);
    bfly1(r[0], r[4]);  bflyw(r[1], r[5], C8f, C8f);  bflyI(r[2], r[6]);  bflyw(r[3], r[7], -C8f, C8f);
    bfly1(r[8], r[12]); bflyw(r[9], r[13], C8f, C8f); bflyI(r[10], r[14]); bflyw(r[11], r[15], -C8f, C8f);
    bfly1(r[0], r[8]);
    bflyw(r[1], r[9],  C16f, S16f);
    bflyw(r[2], r[10], C8f,  C8f);
    bflyw(r[3], r[11], S16f, C16f);
    bflyI(r[4], r[12]);
    bflyw(r[5], r[13], -S16f, C16f);
    bflyw(r[6], r[14], -C8f,  C8f);
    bflyw(r[7], r[15], -C16f, S16f);
}

// LDS XOR swizzle: bijective on [0,4096)
__device__ __forceinline__ int swz(int a) { return a ^ ((a >> 5) & 31); }

__device__ __forceinline__ void fft4096_lds(float* bre, float* bim, int t, float2 r[16],
                                            const int* rv) {
    // ---- phase 1: 16-pt over n1, column n2 = t ----
    #pragma unroll
    for (int n1 = 0; n1 < 16; ++n1) {
        int a = swz(256 * n1 + t);
        r[rv[n1]] = make_float2(bre[a], bim[a]);
    }
    fft16(r);
    {
        float s, c;
        sincosf((float)t * 1.5339807878856412e-3f, &s, &c);   // 2*pi/4096
        float2 w = make_float2(c, s), cur = make_float2(1.f, 0.f);
        #pragma unroll
        for (int k = 0; k < 16; ++k) {
            float xr = r[k].x * cur.x - r[k].y * cur.y;
            float xi = r[k].x * cur.y + r[k].y * cur.x;
            r[k].x = xr; r[k].y = xi;
            float nr = cur.x * w.x - cur.y * w.y;
            float ni = cur.x * w.y + cur.y * w.x;
            cur.x = nr; cur.y = ni;
        }
    }
    #pragma unroll
    for (int k = 0; k < 16; ++k) {
        int a = swz(256 * k + t);
        bre[a] = r[k].x; bim[a] = r[k].y;
    }
    __syncthreads();

    // ---- phase 2 ----
    const int k1 = t >> 4;
    const int lo = t & 15;
    const int base2 = 256 * k1 + lo;
    #pragma unroll
    for (int m1 = 0; m1 < 16; ++m1) {
        int a = swz(base2 + 16 * m1);
        r[rv[m1]] = make_float2(bre[a], bim[a]);
    }
    fft16(r);
    {
        float s, c;
        sincosf((float)lo * 2.45436926061702596e-2f, &s, &c); // 2*pi/256
        float2 w = make_float2(c, s), cur = make_float2(1.f, 0.f);
        #pragma unroll
        for (int k = 0; k < 16; ++k) {
            float xr = r[k].x * cur.x - r[k].y * cur.y;
            float xi = r[k].x * cur.y + r[k].y * cur.x;
            r[k].x = xr; r[k].y = xi;
            float nr = cur.x * w.x - cur.y * w.y;
            float ni = cur.x * w.y + cur.y * w.x;
            cur.x = nr; cur.y = ni;
        }
    }
    #pragma unroll
    for (int k = 0; k < 16; ++k) {
        int a = swz(base2 + 16 * k);
        bre[a] = r[k].x; bim[a] = r[k].y;
    }
    __syncthreads();

    // ---- phase 3 ----
    const int base3 = 256 * k1 + 16 * lo;
    #pragma unroll
    for (int m = 0; m < 16; ++m) {
        int a = swz(base3 + m);
        r[rv[m]] = make_float2(bre[a], bim[a]);
    }
    fft16(r);
    __syncthreads();   // all reads done before digit-swap scatter overwrites
}

// ---------------- pass 1: Hermitian-symmetrized scatter + 4096-pt IFFT over u ----------------
// Block vp in [0,2048] builds Sh(u, vp) = 0.5*D(u,vp) + 0.5*conj(D(-u,-vp)) in LDS
// (winner-resolved per original bucket, SINGLE round: kwin aliases bre, kwin2
// aliases bim), then IFFT over u -> B(o, vp). Output TILED width 8.
__global__ void __launch_bounds__(256) ifft_pass1_kernel(const unsigned* __restrict__ start,
                                                         const unsigned* __restrict__ packed,
                                                         const float2* __restrict__ val,
                                                         float2* __restrict__ outp) {
    __shared__ float bre[FFT_N];
    __shared__ float bim[FFT_N];
    unsigned* kwin  = (unsigned*)bre;   // alias: dead before bre is zero-filled
    unsigned* kwin2 = (unsigned*)bim;
    const int t = threadIdx.x;
    const int vp = blockIdx.x;                 // 0..2048
    const int bd = vp;
    const int bm = (4096 - vp) & 4095;         // mirror bucket (== bd for vp=0,2048)
    const bool sameb = (bm == bd);

    const unsigned s0d = start[bd], s1d = start[bd + 1];
    const unsigned s0m = start[bm], s1m = start[bm + 1];

    unsigned pkD[4], pkM[4]; float2 wvD[4], wvM[4];
    bool vldD[4], vldM[4], winD[4], winM[4];
    #pragma unroll
    for (int e = 0; e < 4; ++e) {
        unsigned i = s0d + (unsigned)t + 256u * (unsigned)e;
        vldD[e] = (i < s1d);
        pkD[e] = vldD[e] ? packed[i] : 0u;
        wvD[e] = vldD[e] ? val[i] : make_float2(0.f, 0.f);
        unsigned i2 = s0m + (unsigned)t + 256u * (unsigned)e;
        vldM[e] = (i2 < s1m);
        pkM[e] = vldM[e] ? packed[i2] : 0u;
        wvM[e] = vldM[e] ? val[i2] : make_float2(0.f, 0.f);
    }

    // single-round winner resolution: D -> kwin, M -> kwin2
    for (int j = t; j < FFT_N; j += 256) { kwin[j] = 0u; kwin2[j] = 0u; }
    __syncthreads();
    #pragma unroll
    for (int e = 0; e < 4; ++e)
        if (vldD[e]) atomicMax(&kwin[pkD[e] & 4095u], pkD[e]);
    #pragma unroll
    for (int e = 0; e < 4; ++e)
        if (vldM[e]) atomicMax(&kwin2[pkM[e] & 4095u], pkM[e]);
    __syncthreads();
    #pragma unroll
    for (int e = 0; e < 4; ++e)
        winD[e] = vldD[e] && (kwin[pkD[e] & 4095u] == pkD[e]);
    #pragma unroll
    for (int e = 0; e < 4; ++e)
        winM[e] = vldM[e] && ((sameb ? kwin : kwin2)[pkM[e] & 4095u] == pkM[e]);
    __syncthreads();   // all kwin reads done before bre/bim overwrite

    for (int j = t; j < FFT_N; j += 256) { bre[j] = 0.f; bim[j] = 0.f; }
    __syncthreads();
    // direct scatter: +0.5 * D(u, vp) at u  (winner positions unique)
    #pragma unroll
    for (int e = 0; e < 4; ++e)
        if (winD[e]) {
            int a = swz((int)(pkD[e] & 4095u));
            bre[a] = 0.5f * wvD[e].x; bim[a] = 0.5f * wvD[e].y;
        }
    __syncthreads();
    // mirror scatter: +0.5 * conj(D(u2, -vp)) at (4096-u2)  (RMW; unique positions)
    #pragma unroll
    for (int e = 0; e < 4; ++e)
        if (winM[e]) {
            int u2 = (int)(pkM[e] & 4095u);
            int a = swz((4096 - u2) & 4095);
            bre[a] += 0.5f * wvM[e].x; bim[a] -= 0.5f * wvM[e].y;
        }
    __syncthreads();

    const int rv[16] = {0, 8, 4, 12, 2, 10, 6, 14, 1, 9, 5, 13, 3, 11, 7, 15};
    float2 r[16];
    fft4096_lds(bre, bim, t, r, rv);

    const float scale = 1.0f / 4096.0f;
    const int k1 = t >> 4, lo = t & 15;
    const int outb = k1 + 16 * lo;
    #pragma unroll
    for (int j2 = 0; j2 < 16; ++j2) {
        int a = swz(outb + 256 * j2);
        bre[a] = r[j2].x * scale;
        bim[a] = r[j2].y * scale;
    }
    __syncthreads();

    // tiled write: element (o=j, vp) -> B'[(j>>3)*HCOLS + vp][j&7]
    for (int j = t; j < FFT_N; j += 256) {
        int a = swz(j);
        outp[((size_t)(j >> 3) * HCOLS + vp) * 8 + (j & 7)] = make_float2(bre[a], bim[a]);
    }
}

// ---------------- pass 2 (+ fused x-cast): c2r IFFT over v, TWO rows per block ----------------
// Blocks 0..2047: rows o1=2s, o2=2s+1 via Z = H(o1) + i*H(o2). Blocks 2048..2559:
// grid-stride f32->bf16 cast of x (independent work, overlapped with FFT).
__global__ void __launch_bounds__(256) ifft_pass2_kernel(const float2* __restrict__ data,
                                                         __hip_bfloat16* __restrict__ wout,
                                                         const float4* __restrict__ x,
                                                         ushort4* __restrict__ xb) {
    __shared__ float bre[FFT_N];
    __shared__ float bim[FFT_N];
    const int t = threadIdx.x;
    const int bid = blockIdx.x;

    if (bid >= 2048) {                                // cast branch
        const int n4 = MROWS * IN_F / 4;
        const int stride = 512 * 256;
        for (int i = (bid - 2048) * 256 + t; i < n4; i += stride) {
            float4 v = x[i];
            __hip_bfloat16 a = __float2bfloat16(v.x);
            __hip_bfloat16 b = __float2bfloat16(v.y);
            __hip_bfloat16 c = __float2bfloat16(v.z);
            __hip_bfloat16 d = __float2bfloat16(v.w);
            ushort4 o;
            o.x = *reinterpret_cast<unsigned short*>(&a);
            o.y = *reinterpret_cast<unsigned short*>(&b);
            o.z = *reinterpret_cast<unsigned short*>(&c);
            o.w = *reinterpret_cast<unsigned short*>(&d);
            xb[i] = o;
        }
        return;
    }

    const int s = (bid & 7) * 256 + (bid >> 3);       // XCD-chunked
    const int o1 = 2 * s;
    const float4* __restrict__ gp = (const float4*)
        (data + (size_t)(o1 >> 3) * HCOLS * 8 + (o1 & 7));

    for (int j = t; j < HCOLS; j += 256) {
        float4 h = gp[(size_t)j * 4];                 // h.xy=H1(j), h.zw=H2(j)
        int a = swz(j & 4095);
        bre[a] = h.x - h.w; bim[a] = h.y + h.z;       // Z(j) = H1 + i*H2
        if (j != 0 && j != 2048) {
            int a2 = swz(4096 - j);                   // Z(-j) = conj(H1) + i*conj(H2)
            bre[a2] = h.x + h.w; bim[a2] = h.z - h.y;
        }
    }
    __syncthreads();

    const int rv[16] = {0, 8, 4, 12, 2, 10, 6, 14, 1, 9, 5, 13, 3, 11, 7, 15};
    float2 r[16];
    fft4096_lds(bre, bim, t, r, rv);

    const float scale = 1.0f / 4096.0f;
    const int k1 = t >> 4, lo = t & 15;
    const int outb = k1 + 16 * lo;
    #pragma unroll
    for (int j2 = 0; j2 < 16; ++j2) {
        int a = swz(outb + 256 * j2);
        bre[a] = r[j2].x * scale;                     // w[o1]
        bim[a] = r[j2].y * scale;                     // w[o2]
    }
    __syncthreads();

    __hip_bfloat16* __restrict__ out1 = wout + (size_t)o1 * FFT_N;
    __hip_bfloat16* __restrict__ out2 = wout + (size_t)(o1 + 1) * FFT_N;
    for (int j = t; j < FFT_N; j += 256) {
        int a = swz(j);
        out1[j] = __float2bfloat16(bre[a]);
        out2[j] = __float2bfloat16(bim[a]);
    }
}

// ---------------- bf16 MFMA GEMM: out[M,N] = X[M,K] * W[N,K]^T + bias ----------------
// BM=128, BN=256, BK=64; 8 waves; 3-buffer LDS, depth-2 prefetch, counted vmcnt(6).
// T3 refinement: a1/b1 ds_reads issued INSIDE cluster-1 MFMA region (completion
// enforced by lgkmcnt(0) after BAR(B)) -> only 8 ds_reads exposed upfront.
__device__ __forceinline__ void stage_tile(const __hip_bfloat16* __restrict__ X,
                                           const __hip_bfloat16* __restrict__ W,
                                           __hip_bfloat16* __restrict__ buf,
                                           int m0, int n0, int tt, int wv, int ln) {
    const int k0n = tt * 64;
    __hip_bfloat16* bufB = buf + 8192;
    #pragma unroll
    for (int kk = 0; kk < 2; ++kk) {
        const int s = kk * 512 + wv * 64 + ln;
        const int row = s >> 3;
        const int cc = (s & 7) ^ (row & 7);
        const __hip_bfloat16* g = X + (size_t)(m0 + row) * IN_F + k0n + cc * 8;
        __builtin_amdgcn_global_load_lds(
            (const __attribute__((address_space(1))) void*)g,
            (__attribute__((address_space(3))) void*)(buf + (size_t)(kk * 512 + wv * 64) * 8),
            16, 0, 0);
    }
    #pragma unroll
    for (int u = 0; u < 2; ++u)
        #pragma unroll
        for (int kk = 0; kk < 2; ++kk) {
            const int s = kk * 512 + wv * 64 + ln;
            const int row = u * 128 + (s >> 3);
            const int cc = (s & 7) ^ (row & 7);
            const __hip_bfloat16* g = W + (size_t)(n0 + row) * IN_F + k0n + cc * 8;
            __builtin_amdgcn_global_load_lds(
                (const __attribute__((address_space(1))) void*)g,
                (__attribute__((address_space(3))) void*)(bufB + (size_t)(u * 1024 + kk * 512 + wv * 64) * 8),
                16, 0, 0);
        }
}

__global__ void __launch_bounds__(512, 2) gemm_kernel(const __hip_bfloat16* __restrict__ X,
                                                      const __hip_bfloat16* __restrict__ W,
                                                      const float* __restrict__ bias,
                                                      float* __restrict__ out) {
    __shared__ __align__(16) __hip_bfloat16 smem[3 * 24576];   // 144 KB
    const int tid = threadIdx.x;
    const int wv = tid >> 6;        // wave 0..7
    const int ln = tid & 63;
    const int m0 = blockIdx.y * 128;
    const int n0 = blockIdx.x * 256;
    const int wm = wv >> 2, wn = wv & 3;
    const int r16 = ln & 15, kg = ln >> 4;
    const int x7 = ln & 7;

    f32x4 acc[4][4];
    #pragma unroll
    for (int i = 0; i < 4; ++i)
        #pragma unroll
        for (int j = 0; j < 4; ++j) acc[i][j] = (f32x4){0.f, 0.f, 0.f, 0.f};

    stage_tile(X, W, smem, m0, n0, 0, wv, ln);
    stage_tile(X, W, smem + 24576, m0, n0, 1, wv, ln);
    asm volatile("s_waitcnt vmcnt(6)" ::: "memory");   // tile 0 landed
    __builtin_amdgcn_s_barrier();

    for (int t = 0; t < 64; ++t) {
        const __hip_bfloat16* Ab = smem + (t % 3) * 24576;
        const __hip_bfloat16* Bb = Ab + 8192;

        // phase A: k-half-0 fragment reads only + prefetch issue for tile t+2
        bf16x8 a0[4], b0[4];
        #pragma unroll
        for (int i = 0; i < 4; ++i) {
            const int R = wm * 64 + i * 16 + r16;
            a0[i] = *reinterpret_cast<const bf16x8*>(Ab + R * 64 + ((kg ^ x7) << 3));
        }
        #pragma unroll
        for (int j = 0; j < 4; ++j) {
            const int R = wn * 64 + j * 16 + r16;
            b0[j] = *reinterpret_cast<const bf16x8*>(Bb + R * 64 + ((kg ^ x7) << 3));
        }
        if (t < 62)
            stage_tile(X, W, smem + ((t + 2) % 3) * 24576, m0, n0, t + 2, wv, ln);

        __builtin_amdgcn_s_barrier();                          // BAR(A)
        asm volatile("s_waitcnt lgkmcnt(0)" ::: "memory");
        __builtin_amdgcn_sched_barrier(0);
        __builtin_amdgcn_s_setprio(1);
        #pragma unroll
        for (int i = 0; i < 2; ++i)
            #pragma unroll
            for (int j = 0; j < 4; ++j)
                acc[i][j] = __builtin_amdgcn_mfma_f32_16x16x32_bf16(a0[i], b0[j], acc[i][j], 0, 0, 0);
        // issue k-half-1 reads; they interleave with the remaining 8 MFMAs
        bf16x8 a1[4], b1[4];
        #pragma unroll
        for (int i = 0; i < 4; ++i) {
            const int R = wm * 64 + i * 16 + r16;
            a1[i] = *reinterpret_cast<const bf16x8*>(Ab + R * 64 + (((4 | kg) ^ x7) << 3));
        }
        #pragma unroll
        for (int j = 0; j < 4; ++j) {
            const int R = wn * 64 + j * 16 + r16;
            b1[j] = *reinterpret_cast<const bf16x8*>(Bb + R * 64 + (((4 | kg) ^ x7) << 3));
        }
        #pragma unroll
        for (int i = 2; i < 4; ++i)
            #pragma unroll
            for (int j = 0; j < 4; ++j)
                acc[i][j] = __builtin_amdgcn_mfma_f32_16x16x32_bf16(a0[i], b0[j], acc[i][j], 0, 0, 0);
        __builtin_amdgcn_s_setprio(0);

        if (t < 62) {
            asm volatile("s_waitcnt vmcnt(6)" ::: "memory");
        } else if (t == 62) {
            asm volatile("s_waitcnt vmcnt(0)" ::: "memory");
        }
        __builtin_amdgcn_s_barrier();                          // BAR(B)
        asm volatile("s_waitcnt lgkmcnt(0)" ::: "memory");     // a1/b1 landed
        __builtin_amdgcn_sched_barrier(0);

        __builtin_amdgcn_s_setprio(1);
        #pragma unroll
        for (int i = 0; i < 4; ++i)
            #pragma unroll
            for (int j = 0; j < 4; ++j)
                acc[i][j] = __builtin_amdgcn_mfma_f32_16x16x32_bf16(a1[i], b1[j], acc[i][j], 0, 0, 0);
        __builtin_amdgcn_s_setprio(0);
    }

    // epilogue: D[m][n], n = lane&15, m = (lane>>4)*4 + e
    #pragma unroll
    for (int i = 0; i < 4; ++i)
        #pragma unroll
        for (int j = 0; j < 4; ++j) {
            const int n = n0 + wn * 64 + j * 16 + r16;
            const float bs = bias[n];
            #pragma unroll
            for (int e = 0; e < 4; ++e) {
                const int m = m0 + wm * 64 + i * 16 + kg * 4 + e;
                out[(size_t)m * OUT_F + n] = acc[i][j][e] + bs;
            }
        }
}

extern "C" void kernel_launch(void* const* d_in, const int* in_sizes, int n_in,
                              void* d_out, int out_size, void* d_ws, size_t ws_size,
                              hipStream_t stream) {
    const float* x    = (const float*)d_in[0];
    const float* sre  = (const float*)d_in[1];
    const float* sim  = (const float*)d_in[2];
    const int*   sidx = (const int*)d_in[3];
    const float* bias = (const float*)d_in[4];
    const int nnz = in_sizes[1];
    float* out = (float*)d_out;

    char* ws = (char*)d_ws;
    // A (tiled intermediate B', 4096 x 2049 complex = 67.1 MB) @ 0
    float2* A = (float2*)ws;
    // bucket arrays alias the Wb region (dead before pass 2 writes Wb)
    unsigned* packed = (unsigned*)(ws + 134217728);                       // 4*nnz
    float2* bval = (float2*)(ws + 134217728 + 4194304);                   // 8*nnz
    __hip_bfloat16* Wb = (__hip_bfloat16*)(ws + 134217728);               // 33.5 MB (pass2 out)
    __hip_bfloat16* Xb = (__hip_bfloat16*)(ws + 134217728 + 33554432);    // 16.8 MB
    char* ctl = ws + 134217728 + 33554432 + 16777216;
    unsigned* cnt   = (unsigned*)(ctl);            // 4096
    unsigned* start = (unsigned*)(ctl + 32768);    // 4097
    unsigned* pos   = (unsigned*)(ctl + 65536);    // 4096

    hipMemsetAsync(cnt, 0, 4096 * sizeof(unsigned), stream);

    const int sb = (nnz + 255) / 256;
    hist_kernel<<<sb, 256, 0, stream>>>(sidx, cnt, nnz);
    scan_kernel<<<1, 256, 0, stream>>>(cnt, start, pos);
    bucket_scatter_kernel<<<sb, 256, 0, stream>>>(sidx, sre, sim, pos, packed, bval, nnz);

    // pass 1: Hermitian-symmetrized scatter + IFFT over u; columns 0..2048 only
    ifft_pass1_kernel<<<HCOLS, 256, 0, stream>>>(start, packed, bval, A);
    // pass 2 (+ fused x-cast): c2r IFFT over v, two rows per block -> bf16 weight
    ifft_pass2_kernel<<<2560, 256, 0, stream>>>(A, Wb, (const float4*)x, (ushort4*)Xb);

    gemm_kernel<<<dim3(OUT_F / 256, MROWS / 128), 512, 0, stream>>>(Xb, Wb, bias, out);
}

// Round 10
// 187.983 us; speedup vs baseline: 1.8697x; 1.3486x over previous
//
#include <hip/hip_runtime.h>
#include <hip/hip_bf16.h>

#define OUT_F 4096
#define IN_F 4096
#define MROWS 2048            // 4*512 batch rows
#define FFT_N 4096
#define HCOLS 2049            // Hermitian-reduced column count
#define BCAP 1024             // fixed bucket capacity (expected max ~300)

typedef short bf16x8 __attribute__((ext_vector_type(8)));
typedef float f32x4 __attribute__((ext_vector_type(4)));

// ================= bucket build: direct fixed-capacity scatter =================
__global__ void bucket_scatter_kernel(const int* __restrict__ idx, const float* __restrict__ re,
                                      const float* __restrict__ im, unsigned* __restrict__ pos,
                                      unsigned* __restrict__ packed, float2* __restrict__ val,
                                      int nnz) {
    int k = blockIdx.x * blockDim.x + threadIdx.x;
    if (k < nnz) {
        int id = idx[k];
        unsigned v = (unsigned)id & (IN_F - 1);
        unsigned u = (unsigned)id >> 12;
        unsigned p = atomicAdd(&pos[v], 1u);
        if (p < BCAP) {
            packed[v * BCAP + p] = ((unsigned)k << 12) | u;   // k high -> max(packed)==max(k)
            val[v * BCAP + p] = make_float2(re[k], im[k]);
        }
    }
}

// ================= 16-pt inverse FFT building blocks =================
__device__ __forceinline__ void bflyw(float2& a, float2& b, float wr, float wi) {
    float tr = b.x * wr - b.y * wi;
    float ti = b.x * wi + b.y * wr;
    b.x = a.x - tr; b.y = a.y - ti;
    a.x += tr; a.y += ti;
}
__device__ __forceinline__ void bfly1(float2& a, float2& b) {   // w = 1
    float tr = b.x, ti = b.y;
    b.x = a.x - tr; b.y = a.y - ti;
    a.x += tr; a.y += ti;
}
__device__ __forceinline__ void bflyI(float2& a, float2& b) {   // w = +i
    float tr = -b.y, ti = b.x;
    b.x = a.x - tr; b.y = a.y - ti;
    a.x += tr; a.y += ti;
}

#define C8f  0.70710678118654752f
#define C16f 0.92387953251128676f
#define S16f 0.38268343236508977f

// inverse 16-pt FFT (+i convention). Input in bit-reversed slots, output natural.
__device__ __forceinline__ void fft16(float2 r[16]) {
    bfly1(r[0], r[1]);  bfly1(r[2], r[3]);  bfly1(r[4], r[5]);   bfly1(r[6], r[7]);
    bfly1(r[8], r[9]);  bfly1(r[10], r[11]); bfly1(r[12], r[13]); bfly1(r[14], r[15]);
    bfly1(r[0], r[2]);  bflyI(r[1], r[3]);
    bfly1(r[4], r[6]);  bflyI(r[5], r[7]);
    bfly1(r[8], r[10]); bflyI(r[9], r[11]);
    bfly1(r[12], r[14]); bflyI(r[13], r[15]);
    bfly1(r[0], r[4]);  bflyw(r[1], r[5], C8f, C8f);  bflyI(r[2], r[6]);  bflyw(r[3], r[7], -C8f, C8f);
    bfly1(r[8], r[12]); bflyw(r[9], r[13], C8f, C8f); bflyI(r[10], r[14]); bflyw(r[11], r[15], -C8f, C8f);
    bfly1(r[0], r[8]);
    bflyw(r[1], r[9],  C16f, S16f);
    bflyw(r[2], r[10], C8f,  C8f);
    bflyw(r[3], r[11], S16f, C16f);
    bflyI(r[4], r[12]);
    bflyw(r[5], r[13], -S16f, C16f);
    bflyw(r[6], r[14], -C8f,  C8f);
    bflyw(r[7], r[15], -C16f, S16f);
}

// LDS XOR swizzle: bijective on [0,4096)
__device__ __forceinline__ int swz(int a) { return a ^ ((a >> 5) & 31); }

__device__ __forceinline__ unsigned packbf2(float re, float im) {
    __hip_bfloat16 r = __float2bfloat16(re), i = __float2bfloat16(im);
    unsigned short rb = *reinterpret_cast<unsigned short*>(&r);
    unsigned short ib = *reinterpret_cast<unsigned short*>(&i);
    return ((unsigned)ib << 16) | (unsigned)rb;
}
__device__ __forceinline__ float bflo(unsigned p) { return __uint_as_float(p << 16); }
__device__ __forceinline__ float bfhi(unsigned p) { return __uint_as_float(p & 0xffff0000u); }

__device__ __forceinline__ void fft4096_lds(float* bre, float* bim, int t, float2 r[16],
                                            const int* rv) {
    // ---- phase 1: 16-pt over n1, column n2 = t ----
    #pragma unroll
    for (int n1 = 0; n1 < 16; ++n1) {
        int a = swz(256 * n1 + t);
        r[rv[n1]] = make_float2(bre[a], bim[a]);
    }
    fft16(r);
    {
        float s, c;
        sincosf((float)t * 1.5339807878856412e-3f, &s, &c);   // 2*pi/4096
        float2 w = make_float2(c, s), cur = make_float2(1.f, 0.f);
        #pragma unroll
        for (int k = 0; k < 16; ++k) {
            float xr = r[k].x * cur.x - r[k].y * cur.y;
            float xi = r[k].x * cur.y + r[k].y * cur.x;
            r[k].x = xr; r[k].y = xi;
            float nr = cur.x * w.x - cur.y * w.y;
            float ni = cur.x * w.y + cur.y * w.x;
            cur.x = nr; cur.y = ni;
        }
    }
    #pragma unroll
    for (int k = 0; k < 16; ++k) {
        int a = swz(256 * k + t);
        bre[a] = r[k].x; bim[a] = r[k].y;
    }
    __syncthreads();

    // ---- phase 2 ----
    const int k1 = t >> 4;
    const int lo = t & 15;
    const int base2 = 256 * k1 + lo;
    #pragma unroll
    for (int m1 = 0; m1 < 16; ++m1) {
        int a = swz(base2 + 16 * m1);
        r[rv[m1]] = make_float2(bre[a], bim[a]);
    }
    fft16(r);
    {
        float s, c;
        sincosf((float)lo * 2.45436926061702596e-2f, &s, &c); // 2*pi/256
        float2 w = make_float2(c, s), cur = make_float2(1.f, 0.f);
        #pragma unroll
        for (int k = 0; k < 16; ++k) {
            float xr = r[k].x * cur.x - r[k].y * cur.y;
            float xi = r[k].x * cur.y + r[k].y * cur.x;
            r[k].x = xr; r[k].y = xi;
            float nr = cur.x * w.x - cur.y * w.y;
            float ni = cur.x * w.y + cur.y * w.x;
            cur.x = nr; cur.y = ni;
        }
    }
    #pragma unroll
    for (int k = 0; k < 16; ++k) {
        int a = swz(base2 + 16 * k);
        bre[a] = r[k].x; bim[a] = r[k].y;
    }
    __syncthreads();

    // ---- phase 3 ----
    const int base3 = 256 * k1 + 16 * lo;
    #pragma unroll
    for (int m = 0; m < 16; ++m) {
        int a = swz(base3 + m);
        r[rv[m]] = make_float2(bre[a], bim[a]);
    }
    fft16(r);
    __syncthreads();   // all reads done before digit-swap scatter overwrites
}

// ---------------- pass 1: Hermitian-symmetrized scatter + 4096-pt IFFT over u ----------------
// Block vp in [0,2048] builds Sh(u, vp) = 0.5*D(u,vp) + 0.5*conj(D(-u,-vp)) in LDS
// (winner-resolved, single round: kwin aliases bre, kwin2 aliases bim), IFFT over u,
// output bf16-packed (re|im in 4 B), TILED width 8: B'[o>>3][vp][o&7].
__global__ void __launch_bounds__(256) ifft_pass1_kernel(const unsigned* __restrict__ pos,
                                                         const unsigned* __restrict__ packed,
                                                         const float2* __restrict__ val,
                                                         unsigned* __restrict__ outp) {
    __shared__ float bre[FFT_N];
    __shared__ float bim[FFT_N];
    unsigned* kwin  = (unsigned*)bre;   // alias: dead before bre is zero-filled
    unsigned* kwin2 = (unsigned*)bim;
    const int t = threadIdx.x;
    const int vp = blockIdx.x;                 // 0..2048
    const int bd = vp;
    const int bm = (4096 - vp) & 4095;         // mirror bucket (== bd for vp=0,2048)
    const bool sameb = (bm == bd);

    const unsigned cd = min(pos[bd], (unsigned)BCAP);
    const unsigned cm = min(pos[bm], (unsigned)BCAP);
    const unsigned b0d = (unsigned)bd * BCAP, b0m = (unsigned)bm * BCAP;

    unsigned pkD[4], pkM[4]; float2 wvD[4], wvM[4];
    bool vldD[4], vldM[4], winD[4], winM[4];
    #pragma unroll
    for (int e = 0; e < 4; ++e) {
        unsigned o = (unsigned)t + 256u * (unsigned)e;
        vldD[e] = (o < cd);
        pkD[e] = vldD[e] ? packed[b0d + o] : 0u;
        wvD[e] = vldD[e] ? val[b0d + o] : make_float2(0.f, 0.f);
        vldM[e] = (o < cm);
        pkM[e] = vldM[e] ? packed[b0m + o] : 0u;
        wvM[e] = vldM[e] ? val[b0m + o] : make_float2(0.f, 0.f);
    }

    // single-round winner resolution: D -> kwin, M -> kwin2
    for (int j = t; j < FFT_N; j += 256) { kwin[j] = 0u; kwin2[j] = 0u; }
    __syncthreads();
    #pragma unroll
    for (int e = 0; e < 4; ++e)
        if (vldD[e]) atomicMax(&kwin[pkD[e] & 4095u], pkD[e]);
    #pragma unroll
    for (int e = 0; e < 4; ++e)
        if (vldM[e]) atomicMax(&kwin2[pkM[e] & 4095u], pkM[e]);
    __syncthreads();
    #pragma unroll
    for (int e = 0; e < 4; ++e)
        winD[e] = vldD[e] && (kwin[pkD[e] & 4095u] == pkD[e]);
    #pragma unroll
    for (int e = 0; e < 4; ++e)
        winM[e] = vldM[e] && ((sameb ? kwin : kwin2)[pkM[e] & 4095u] == pkM[e]);
    __syncthreads();   // all kwin reads done before bre/bim overwrite

    for (int j = t; j < FFT_N; j += 256) { bre[j] = 0.f; bim[j] = 0.f; }
    __syncthreads();
    // direct scatter: +0.5 * D(u, vp) at u  (winner positions unique)
    #pragma unroll
    for (int e = 0; e < 4; ++e)
        if (winD[e]) {
            int a = swz((int)(pkD[e] & 4095u));
            bre[a] = 0.5f * wvD[e].x; bim[a] = 0.5f * wvD[e].y;
        }
    __syncthreads();
    // mirror scatter: +0.5 * conj(D(u2, -vp)) at (4096-u2)  (RMW; unique positions)
    #pragma unroll
    for (int e = 0; e < 4; ++e)
        if (winM[e]) {
            int u2 = (int)(pkM[e] & 4095u);
            int a = swz((4096 - u2) & 4095);
            bre[a] += 0.5f * wvM[e].x; bim[a] -= 0.5f * wvM[e].y;
        }
    __syncthreads();

    const int rv[16] = {0, 8, 4, 12, 2, 10, 6, 14, 1, 9, 5, 13, 3, 11, 7, 15};
    float2 r[16];
    fft4096_lds(bre, bim, t, r, rv);

    const float scale = 1.0f / 4096.0f;
    const int k1 = t >> 4, lo = t & 15;
    const int outb = k1 + 16 * lo;
    #pragma unroll
    for (int j2 = 0; j2 < 16; ++j2) {
        int a = swz(outb + 256 * j2);
        bre[a] = r[j2].x * scale;
        bim[a] = r[j2].y * scale;
    }
    __syncthreads();

    // tiled bf16 write: element (o=j, vp) -> B'[(j>>3)*HCOLS + vp][j&7] (4 B each)
    for (int j = t; j < FFT_N; j += 256) {
        int a = swz(j);
        outp[((size_t)(j >> 3) * HCOLS + vp) * 8 + (j & 7)] = packbf2(bre[a], bim[a]);
    }
}

// ---------------- pass 2 (+ fused x-cast): c2r IFFT over v, TWO rows per block ----------------
// Blocks 0..2047: rows o1=2s, o2=2s+1 via Z = H(o1) + i*H(o2); H read as one uint2
// (two packed bf16x2) per v, byte-contiguous in v. Blocks 2048..2559: x cast.
__global__ void __launch_bounds__(256) ifft_pass2_kernel(const unsigned* __restrict__ data,
                                                         __hip_bfloat16* __restrict__ wout,
                                                         const float4* __restrict__ x,
                                                         ushort4* __restrict__ xb) {
    __shared__ float bre[FFT_N];
    __shared__ float bim[FFT_N];
    const int t = threadIdx.x;
    const int bid = blockIdx.x;

    if (bid >= 2048) {                                // cast branch
        const int n4 = MROWS * IN_F / 4;
        const int stride = 512 * 256;
        for (int i = (bid - 2048) * 256 + t; i < n4; i += stride) {
            float4 v = x[i];
            __hip_bfloat16 a = __float2bfloat16(v.x);
            __hip_bfloat16 b = __float2bfloat16(v.y);
            __hip_bfloat16 c = __float2bfloat16(v.z);
            __hip_bfloat16 d = __float2bfloat16(v.w);
            ushort4 o;
            o.x = *reinterpret_cast<unsigned short*>(&a);
            o.y = *reinterpret_cast<unsigned short*>(&b);
            o.z = *reinterpret_cast<unsigned short*>(&c);
            o.w = *reinterpret_cast<unsigned short*>(&d);
            xb[i] = o;
        }
        return;
    }

    const int s = (bid & 7) * 256 + (bid >> 3);       // XCD-chunked
    const int o1 = 2 * s;
    const unsigned* __restrict__ gp = data + (size_t)(o1 >> 3) * HCOLS * 8 + (o1 & 7);

    for (int j = t; j < HCOLS; j += 256) {
        uint2 h = *reinterpret_cast<const uint2*>(gp + (size_t)j * 8);
        float h1r = bflo(h.x), h1i = bfhi(h.x);
        float h2r = bflo(h.y), h2i = bfhi(h.y);
        int a = swz(j & 4095);
        bre[a] = h1r - h2i; bim[a] = h1i + h2r;       // Z(j) = H1 + i*H2
        if (j != 0 && j != 2048) {
            int a2 = swz(4096 - j);                   // Z(-j) = conj(H1) + i*conj(H2)
            bre[a2] = h1r + h2i; bim[a2] = h2r - h1i;
        }
    }
    __syncthreads();

    const int rv[16] = {0, 8, 4, 12, 2, 10, 6, 14, 1, 9, 5, 13, 3, 11, 7, 15};
    float2 r[16];
    fft4096_lds(bre, bim, t, r, rv);

    const float scale = 1.0f / 4096.0f;
    const int k1 = t >> 4, lo = t & 15;
    const int outb = k1 + 16 * lo;
    #pragma unroll
    for (int j2 = 0; j2 < 16; ++j2) {
        int a = swz(outb + 256 * j2);
        bre[a] = r[j2].x * scale;                     // w[o1]
        bim[a] = r[j2].y * scale;                     // w[o2]
    }
    __syncthreads();

    __hip_bfloat16* __restrict__ out1 = wout + (size_t)o1 * FFT_N;
    __hip_bfloat16* __restrict__ out2 = wout + (size_t)(o1 + 1) * FFT_N;
    for (int j = t; j < FFT_N; j += 256) {
        int a = swz(j);
        out1[j] = __float2bfloat16(bre[a]);
        out2[j] = __float2bfloat16(bim[a]);
    }
}

// ---------------- bf16 MFMA GEMM (unchanged from R9) ----------------
__device__ __forceinline__ void stage_tile(const __hip_bfloat16* __restrict__ X,
                                           const __hip_bfloat16* __restrict__ W,
                                           __hip_bfloat16* __restrict__ buf,
                                           int m0, int n0, int tt, int wv, int ln) {
    const int k0n = tt * 64;
    __hip_bfloat16* bufB = buf + 8192;
    #pragma unroll
    for (int kk = 0; kk < 2; ++kk) {
        const int s = kk * 512 + wv * 64 + ln;
        const int row = s >> 3;
        const int cc = (s & 7) ^ (row & 7);
        const __hip_bfloat16* g = X + (size_t)(m0 + row) * IN_F + k0n + cc * 8;
        __builtin_amdgcn_global_load_lds(
            (const __attribute__((address_space(1))) void*)g,
            (__attribute__((address_space(3))) void*)(buf + (size_t)(kk * 512 + wv * 64) * 8),
            16, 0, 0);
    }
    #pragma unroll
    for (int u = 0; u < 2; ++u)
        #pragma unroll
        for (int kk = 0; kk < 2; ++kk) {
            const int s = kk * 512 + wv * 64 + ln;
            const int row = u * 128 + (s >> 3);
            const int cc = (s & 7) ^ (row & 7);
            const __hip_bfloat16* g = W + (size_t)(n0 + row) * IN_F + k0n + cc * 8;
            __builtin_amdgcn_global_load_lds(
                (const __attribute__((address_space(1))) void*)g,
                (__attribute__((address_space(3))) void*)(bufB + (size_t)(u * 1024 + kk * 512 + wv * 64) * 8),
                16, 0, 0);
        }
}

__global__ void __launch_bounds__(512, 2) gemm_kernel(const __hip_bfloat16* __restrict__ X,
                                                      const __hip_bfloat16* __restrict__ W,
                                                      const float* __restrict__ bias,
                                                      float* __restrict__ out) {
    __shared__ __align__(16) __hip_bfloat16 smem[3 * 24576];   // 144 KB
    const int tid = threadIdx.x;
    const int wv = tid >> 6;        // wave 0..7
    const int ln = tid & 63;
    const int m0 = blockIdx.y * 128;
    const int n0 = blockIdx.x * 256;
    const int wm = wv >> 2, wn = wv & 3;
    const int r16 = ln & 15, kg = ln >> 4;
    const int x7 = ln & 7;

    f32x4 acc[4][4];
    #pragma unroll
    for (int i = 0; i < 4; ++i)
        #pragma unroll
        for (int j = 0; j < 4; ++j) acc[i][j] = (f32x4){0.f, 0.f, 0.f, 0.f};

    stage_tile(X, W, smem, m0, n0, 0, wv, ln);
    stage_tile(X, W, smem + 24576, m0, n0, 1, wv, ln);
    asm volatile("s_waitcnt vmcnt(6)" ::: "memory");   // tile 0 landed
    __builtin_amdgcn_s_barrier();

    for (int t = 0; t < 64; ++t) {
        const __hip_bfloat16* Ab = smem + (t % 3) * 24576;
        const __hip_bfloat16* Bb = Ab + 8192;

        // phase A: k-half-0 fragment reads only + prefetch issue for tile t+2
        bf16x8 a0[4], b0[4];
        #pragma unroll
        for (int i = 0; i < 4; ++i) {
            const int R = wm * 64 + i * 16 + r16;
            a0[i] = *reinterpret_cast<const bf16x8*>(Ab + R * 64 + ((kg ^ x7) << 3));
        }
        #pragma unroll
        for (int j = 0; j < 4; ++j) {
            const int R = wn * 64 + j * 16 + r16;
            b0[j] = *reinterpret_cast<const bf16x8*>(Bb + R * 64 + ((kg ^ x7) << 3));
        }
        if (t < 62)
            stage_tile(X, W, smem + ((t + 2) % 3) * 24576, m0, n0, t + 2, wv, ln);

        __builtin_amdgcn_s_barrier();                          // BAR(A)
        asm volatile("s_waitcnt lgkmcnt(0)" ::: "memory");
        __builtin_amdgcn_sched_barrier(0);
        __builtin_amdgcn_s_setprio(1);
        #pragma unroll
        for (int i = 0; i < 2; ++i)
            #pragma unroll
            for (int j = 0; j < 4; ++j)
                acc[i][j] = __builtin_amdgcn_mfma_f32_16x16x32_bf16(a0[i], b0[j], acc[i][j], 0, 0, 0);
        // issue k-half-1 reads; they interleave with the remaining 8 MFMAs
        bf16x8 a1[4], b1[4];
        #pragma unroll
        for (int i = 0; i < 4; ++i) {
            const int R = wm * 64 + i * 16 + r16;
            a1[i] = *reinterpret_cast<const bf16x8*>(Ab + R * 64 + (((4 | kg) ^ x7) << 3));
        }
        #pragma unroll
        for (int j = 0; j < 4; ++j) {
            const int R = wn * 64 + j * 16 + r16;
            b1[j] = *reinterpret_cast<const bf16x8*>(Bb + R * 64 + (((4 | kg) ^ x7) << 3));
        }
        #pragma unroll
        for (int i = 2; i < 4; ++i)
            #pragma unroll
            for (int j = 0; j < 4; ++j)
                acc[i][j] = __builtin_amdgcn_mfma_f32_16x16x32_bf16(a0[i], b0[j], acc[i][j], 0, 0, 0);
        __builtin_amdgcn_s_setprio(0);

        if (t < 62) {
            asm volatile("s_waitcnt vmcnt(6)" ::: "memory");
        } else if (t == 62) {
            asm volatile("s_waitcnt vmcnt(0)" ::: "memory");
        }
        __builtin_amdgcn_s_barrier();                          // BAR(B)
        asm volatile("s_waitcnt lgkmcnt(0)" ::: "memory");     // a1/b1 landed
        __builtin_amdgcn_sched_barrier(0);

        __builtin_amdgcn_s_setprio(1);
        #pragma unroll
        for (int i = 0; i < 4; ++i)
            #pragma unroll
            for (int j = 0; j < 4; ++j)
                acc[i][j] = __builtin_amdgcn_mfma_f32_16x16x32_bf16(a1[i], b1[j], acc[i][j], 0, 0, 0);
        __builtin_amdgcn_s_setprio(0);
    }

    // epilogue: D[m][n], n = lane&15, m = (lane>>4)*4 + e
    #pragma unroll
    for (int i = 0; i < 4; ++i)
        #pragma unroll
        for (int j = 0; j < 4; ++j) {
            const int n = n0 + wn * 64 + j * 16 + r16;
            const float bs = bias[n];
            #pragma unroll
            for (int e = 0; e < 4; ++e) {
                const int m = m0 + wm * 64 + i * 16 + kg * 4 + e;
                out[(size_t)m * OUT_F + n] = acc[i][j][e] + bs;
            }
        }
}

extern "C" void kernel_launch(void* const* d_in, const int* in_sizes, int n_in,
                              void* d_out, int out_size, void* d_ws, size_t ws_size,
                              hipStream_t stream) {
    const float* x    = (const float*)d_in[0];
    const float* sre  = (const float*)d_in[1];
    const float* sim  = (const float*)d_in[2];
    const int*   sidx = (const int*)d_in[3];
    const float* bias = (const float*)d_in[4];
    const int nnz = in_sizes[1];
    float* out = (float*)d_out;

    char* ws = (char*)d_ws;
    // A (tiled bf16-packed intermediate, 2049*4096 u32 = 33.6 MB) @ 0
    unsigned* A = (unsigned*)ws;
    // bucket arrays alias the Wb region (dead before pass 2 writes Wb)
    unsigned* packed = (unsigned*)(ws + 134217728);                       // 16.8 MB
    float2* bval = (float2*)(ws + 134217728 + 16777216);                  // 33.6 MB
    __hip_bfloat16* Wb = (__hip_bfloat16*)(ws + 134217728);               // 33.5 MB (pass2 out)
    __hip_bfloat16* Xb = (__hip_bfloat16*)(ws + 67108864);                // 16.8 MB
    unsigned* pos = (unsigned*)(ws + 100663296);                          // 16 KB

    hipMemsetAsync(pos, 0, 4096 * sizeof(unsigned), stream);

    const int sb = (nnz + 255) / 256;
    bucket_scatter_kernel<<<sb, 256, 0, stream>>>(sidx, sre, sim, pos, packed, bval, nnz);

    // pass 1: Hermitian-symmetrized scatter + IFFT over u; columns 0..2048 only
    ifft_pass1_kernel<<<HCOLS, 256, 0, stream>>>(pos, packed, bval, A);
    // pass 2 (+ fused x-cast): c2r IFFT over v, two rows per block -> bf16 weight
    ifft_pass2_kernel<<<2560, 256, 0, stream>>>(A, Wb, (const float4*)x, (ushort4*)Xb);

    gemm_kernel<<<dim3(OUT_F / 256, MROWS / 128), 512, 0, stream>>>(Xb, Wb, bias, out);
}

// Round 11
// 187.021 us; speedup vs baseline: 1.8793x; 1.0051x over previous
//
#include <hip/hip_runtime.h>
#include <hip/hip_bf16.h>

#define OUT_F 4096
#define IN_F 4096
#define MROWS 2048            // 4*512 batch rows
#define FFT_N 4096
#define HCOLS 2049            // Hermitian-reduced column count
#define BCAP 1024             // fixed bucket capacity (expected max ~300)

typedef short bf16x8 __attribute__((ext_vector_type(8)));
typedef float f32x4 __attribute__((ext_vector_type(4)));

// ================= bucket build: direct fixed-capacity scatter, 16-B entries =================
__global__ void bucket_scatter_kernel(const int* __restrict__ idx, const float* __restrict__ re,
                                      const float* __restrict__ im, unsigned* __restrict__ pos,
                                      uint4* __restrict__ bkt, int nnz) {
    int k = blockIdx.x * blockDim.x + threadIdx.x;
    if (k < nnz) {
        int id = idx[k];
        unsigned v = (unsigned)id & (IN_F - 1);
        unsigned u = (unsigned)id >> 12;
        unsigned p = atomicAdd(&pos[v], 1u);
        if (p < BCAP) {
            // one 16-B store -> one cache line touched per entry
            bkt[v * BCAP + p] = make_uint4(((unsigned)k << 12) | u,
                                           __float_as_uint(re[k]),
                                           __float_as_uint(im[k]), 0u);
        }
    }
}

// ================= 16-pt inverse FFT building blocks =================
__device__ __forceinline__ float2 cmul(float2 a, float2 b) {
    return make_float2(a.x * b.x - a.y * b.y, a.x * b.y + a.y * b.x);
}
__device__ __forceinline__ void bflyw(float2& a, float2& b, float wr, float wi) {
    float tr = b.x * wr - b.y * wi;
    float ti = b.x * wi + b.y * wr;
    b.x = a.x - tr; b.y = a.y - ti;
    a.x += tr; a.y += ti;
}
__device__ __forceinline__ void bfly1(float2& a, float2& b) {   // w = 1
    float tr = b.x, ti = b.y;
    b.x = a.x - tr; b.y = a.y - ti;
    a.x += tr; a.y += ti;
}
__device__ __forceinline__ void bflyI(float2& a, float2& b) {   // w = +i
    float tr = -b.y, ti = b.x;
    b.x = a.x - tr; b.y = a.y - ti;
    a.x += tr; a.y += ti;
}

#define C8f  0.70710678118654752f
#define C16f 0.92387953251128676f
#define S16f 0.38268343236508977f

// inverse 16-pt FFT (+i convention). Input in bit-reversed slots, output natural.
__device__ __forceinline__ void fft16(float2 r[16]) {
    bfly1(r[0], r[1]);  bfly1(r[2], r[3]);  bfly1(r[4], r[5]);   bfly1(r[6], r[7]);
    bfly1(r[8], r[9]);  bfly1(r[10], r[11]); bfly1(r[12], r[13]); bfly1(r[14], r[15]);
    bfly1(r[0], r[2]);  bflyI(r[1], r[3]);
    bfly1(r[4], r[6]);  bflyI(r[5], r[7]);
    bfly1(r[8], r[10]); bflyI(r[9], r[11]);
    bfly1(r[12], r[14]); bflyI(r[13], r[15]);
    bfly1(r[0], r[4]);  bflyw(r[1], r[5], C8f, C8f);  bflyI(r[2], r[6]);  bflyw(r[3], r[7], -C8f, C8f);
    bfly1(r[8], r[12]); bflyw(r[9], r[13], C8f, C8f); bflyI(r[10], r[14]); bflyw(r[11], r[15], -C8f, C8f);
    bfly1(r[0], r[8]);
    bflyw(r[1], r[9],  C16f, S16f);
    bflyw(r[2], r[10], C8f,  C8f);
    bflyw(r[3], r[11], S16f, C16f);
    bflyI(r[4], r[12]);
    bflyw(r[5], r[13], -S16f, C16f);
    bflyw(r[6], r[14], -C8f,  C8f);
    bflyw(r[7], r[15], -C16f, S16f);
}

// depth-4 tree twiddle: r[k] *= w^k, w = exp(i*ang). 15 independent mults
// (depth ~4) instead of a 16-step serial chain.
__device__ __forceinline__ void twiddle16(float2 r[16], float ang) {
    float s, c;
    __sincosf(ang, &s, &c);
    float2 w1 = make_float2(c, s);
    float2 w2 = cmul(w1, w1), w4 = cmul(w2, w2), w8 = cmul(w4, w4);
    float2 cur[16];
    cur[1] = w1; cur[2] = w2; cur[3] = cmul(w2, w1);
    cur[4] = w4; cur[5] = cmul(w4, w1); cur[6] = cmul(w4, w2); cur[7] = cmul(w4, cur[3]);
    #pragma unroll
    for (int k = 0; k < 8; ++k) cur[8 + k] = (k == 0) ? w8 : cmul(w8, cur[k]);
    #pragma unroll
    for (int k = 1; k < 16; ++k) r[k] = cmul(r[k], cur[k]);
}

// LDS XOR swizzle: bijective on [0,4096)
__device__ __forceinline__ int swz(int a) { return a ^ ((a >> 5) & 31); }

__device__ __forceinline__ unsigned packbf2(float re, float im) {
    __hip_bfloat16 r = __float2bfloat16(re), i = __float2bfloat16(im);
    unsigned short rb = *reinterpret_cast<unsigned short*>(&r);
    unsigned short ib = *reinterpret_cast<unsigned short*>(&i);
    return ((unsigned)ib << 16) | (unsigned)rb;
}
__device__ __forceinline__ float bflo(unsigned p) { return __uint_as_float(p << 16); }
__device__ __forceinline__ float bfhi(unsigned p) { return __uint_as_float(p & 0xffff0000u); }

__device__ __forceinline__ void fft4096_lds(float* bre, float* bim, int t, float2 r[16],
                                            const int* rv) {
    // ---- phase 1: 16-pt over n1, column n2 = t ----
    #pragma unroll
    for (int n1 = 0; n1 < 16; ++n1) {
        int a = swz(256 * n1 + t);
        r[rv[n1]] = make_float2(bre[a], bim[a]);
    }
    fft16(r);
    twiddle16(r, (float)t * 1.5339807878856412e-3f);   // 2*pi/4096
    #pragma unroll
    for (int k = 0; k < 16; ++k) {
        int a = swz(256 * k + t);
        bre[a] = r[k].x; bim[a] = r[k].y;
    }
    __syncthreads();

    // ---- phase 2 ----
    const int k1 = t >> 4;
    const int lo = t & 15;
    const int base2 = 256 * k1 + lo;
    #pragma unroll
    for (int m1 = 0; m1 < 16; ++m1) {
        int a = swz(base2 + 16 * m1);
        r[rv[m1]] = make_float2(bre[a], bim[a]);
    }
    fft16(r);
    twiddle16(r, (float)lo * 2.45436926061702596e-2f); // 2*pi/256
    #pragma unroll
    for (int k = 0; k < 16; ++k) {
        int a = swz(base2 + 16 * k);
        bre[a] = r[k].x; bim[a] = r[k].y;
    }
    __syncthreads();

    // ---- phase 3 ----
    const int base3 = 256 * k1 + 16 * lo;
    #pragma unroll
    for (int m = 0; m < 16; ++m) {
        int a = swz(base3 + m);
        r[rv[m]] = make_float2(bre[a], bim[a]);
    }
    fft16(r);
    __syncthreads();   // all reads done before digit-swap scatter overwrites
}

// ---------------- pass 1: Hermitian-symmetrized scatter + 4096-pt IFFT over u ----------------
// Block vp in [0,2048] builds Sh(u, vp) = 0.5*D(u,vp) + 0.5*conj(D(-u,-vp)) in LDS
// (winner-resolved, single round: kwin aliases bre, kwin2 aliases bim), IFFT over u,
// output bf16-packed (re|im in 4 B), TILED width 8: B'[o>>3][vp][o&7].
__global__ void __launch_bounds__(256) ifft_pass1_kernel(const unsigned* __restrict__ pos,
                                                         const uint4* __restrict__ bkt,
                                                         unsigned* __restrict__ outp) {
    __shared__ float bre[FFT_N];
    __shared__ float bim[FFT_N];
    unsigned* kwin  = (unsigned*)bre;   // alias: dead before bre is zero-filled
    unsigned* kwin2 = (unsigned*)bim;
    const int t = threadIdx.x;
    const int vp = blockIdx.x;                 // 0..2048
    const int bd = vp;
    const int bm = (4096 - vp) & 4095;         // mirror bucket (== bd for vp=0,2048)
    const bool sameb = (bm == bd);

    const unsigned cd = min(pos[bd], (unsigned)BCAP);
    const unsigned cm = min(pos[bm], (unsigned)BCAP);
    const unsigned b0d = (unsigned)bd * BCAP, b0m = (unsigned)bm * BCAP;

    unsigned pkD[4], pkM[4]; float2 wvD[4], wvM[4];
    bool vldD[4], vldM[4], winD[4], winM[4];
    #pragma unroll
    for (int e = 0; e < 4; ++e) {
        unsigned o = (unsigned)t + 256u * (unsigned)e;
        vldD[e] = (o < cd);
        uint4 eD = vldD[e] ? bkt[b0d + o] : make_uint4(0u, 0u, 0u, 0u);
        pkD[e] = eD.x;
        wvD[e] = make_float2(__uint_as_float(eD.y), __uint_as_float(eD.z));
        vldM[e] = (o < cm);
        uint4 eM = vldM[e] ? bkt[b0m + o] : make_uint4(0u, 0u, 0u, 0u);
        pkM[e] = eM.x;
        wvM[e] = make_float2(__uint_as_float(eM.y), __uint_as_float(eM.z));
    }

    // single-round winner resolution: D -> kwin, M -> kwin2
    for (int j = t; j < FFT_N; j += 256) { kwin[j] = 0u; kwin2[j] = 0u; }
    __syncthreads();
    #pragma unroll
    for (int e = 0; e < 4; ++e)
        if (vldD[e]) atomicMax(&kwin[pkD[e] & 4095u], pkD[e]);
    #pragma unroll
    for (int e = 0; e < 4; ++e)
        if (vldM[e]) atomicMax(&kwin2[pkM[e] & 4095u], pkM[e]);
    __syncthreads();
    #pragma unroll
    for (int e = 0; e < 4; ++e)
        winD[e] = vldD[e] && (kwin[pkD[e] & 4095u] == pkD[e]);
    #pragma unroll
    for (int e = 0; e < 4; ++e)
        winM[e] = vldM[e] && ((sameb ? kwin : kwin2)[pkM[e] & 4095u] == pkM[e]);
    __syncthreads();   // all kwin reads done before bre/bim overwrite

    for (int j = t; j < FFT_N; j += 256) { bre[j] = 0.f; bim[j] = 0.f; }
    __syncthreads();
    // direct scatter: +0.5 * D(u, vp) at u  (winner positions unique)
    #pragma unroll
    for (int e = 0; e < 4; ++e)
        if (winD[e]) {
            int a = swz((int)(pkD[e] & 4095u));
            bre[a] = 0.5f * wvD[e].x; bim[a] = 0.5f * wvD[e].y;
        }
    __syncthreads();
    // mirror scatter: +0.5 * conj(D(u2, -vp)) at (4096-u2)  (RMW; unique positions)
    #pragma unroll
    for (int e = 0; e < 4; ++e)
        if (winM[e]) {
            int u2 = (int)(pkM[e] & 4095u);
            int a = swz((4096 - u2) & 4095);
            bre[a] += 0.5f * wvM[e].x; bim[a] -= 0.5f * wvM[e].y;
        }
    __syncthreads();

    const int rv[16] = {0, 8, 4, 12, 2, 10, 6, 14, 1, 9, 5, 13, 3, 11, 7, 15};
    float2 r[16];
    fft4096_lds(bre, bim, t, r, rv);

    const float scale = 1.0f / 4096.0f;
    const int k1 = t >> 4, lo = t & 15;
    const int outb = k1 + 16 * lo;
    #pragma unroll
    for (int j2 = 0; j2 < 16; ++j2) {
        int a = swz(outb + 256 * j2);
        bre[a] = r[j2].x * scale;
        bim[a] = r[j2].y * scale;
    }
    __syncthreads();

    // tiled bf16 write: element (o=j, vp) -> B'[(j>>3)*HCOLS + vp][j&7] (4 B each)
    for (int j = t; j < FFT_N; j += 256) {
        int a = swz(j);
        outp[((size_t)(j >> 3) * HCOLS + vp) * 8 + (j & 7)] = packbf2(bre[a], bim[a]);
    }
}

// ---------------- pass 2 (+ fused x-cast): c2r IFFT over v, TWO rows per block ----------------
// Blocks 0..2047: rows o1=2s, o2=2s+1 via Z = H(o1) + i*H(o2); H read as one uint2
// (two packed bf16x2) per v, byte-contiguous in v. Blocks 2048..2559: x cast.
__global__ void __launch_bounds__(256) ifft_pass2_kernel(const unsigned* __restrict__ data,
                                                         __hip_bfloat16* __restrict__ wout,
                                                         const float4* __restrict__ x,
                                                         ushort4* __restrict__ xb) {
    __shared__ float bre[FFT_N];
    __shared__ float bim[FFT_N];
    const int t = threadIdx.x;
    const int bid = blockIdx.x;

    if (bid >= 2048) {                                // cast branch
        const int n4 = MROWS * IN_F / 4;
        const int stride = 512 * 256;
        for (int i = (bid - 2048) * 256 + t; i < n4; i += stride) {
            float4 v = x[i];
            __hip_bfloat16 a = __float2bfloat16(v.x);
            __hip_bfloat16 b = __float2bfloat16(v.y);
            __hip_bfloat16 c = __float2bfloat16(v.z);
            __hip_bfloat16 d = __float2bfloat16(v.w);
            ushort4 o;
            o.x = *reinterpret_cast<unsigned short*>(&a);
            o.y = *reinterpret_cast<unsigned short*>(&b);
            o.z = *reinterpret_cast<unsigned short*>(&c);
            o.w = *reinterpret_cast<unsigned short*>(&d);
            xb[i] = o;
        }
        return;
    }

    const int s = (bid & 7) * 256 + (bid >> 3);       // XCD-chunked
    const int o1 = 2 * s;
    const unsigned* __restrict__ gp = data + (size_t)(o1 >> 3) * HCOLS * 8 + (o1 & 7);

    for (int j = t; j < HCOLS; j += 256) {
        uint2 h = *reinterpret_cast<const uint2*>(gp + (size_t)j * 8);
        float h1r = bflo(h.x), h1i = bfhi(h.x);
        float h2r = bflo(h.y), h2i = bfhi(h.y);
        int a = swz(j & 4095);
        bre[a] = h1r - h2i; bim[a] = h1i + h2r;       // Z(j) = H1 + i*H2
        if (j != 0 && j != 2048) {
            int a2 = swz(4096 - j);                   // Z(-j) = conj(H1) + i*conj(H2)
            bre[a2] = h1r + h2i; bim[a2] = h2r - h1i;
        }
    }
    __syncthreads();

    const int rv[16] = {0, 8, 4, 12, 2, 10, 6, 14, 1, 9, 5, 13, 3, 11, 7, 15};
    float2 r[16];
    fft4096_lds(bre, bim, t, r, rv);

    const float scale = 1.0f / 4096.0f;
    const int k1 = t >> 4, lo = t & 15;
    const int outb = k1 + 16 * lo;
    #pragma unroll
    for (int j2 = 0; j2 < 16; ++j2) {
        int a = swz(outb + 256 * j2);
        bre[a] = r[j2].x * scale;                     // w[o1]
        bim[a] = r[j2].y * scale;                     // w[o2]
    }
    __syncthreads();

    __hip_bfloat16* __restrict__ out1 = wout + (size_t)o1 * FFT_N;
    __hip_bfloat16* __restrict__ out2 = wout + (size_t)(o1 + 1) * FFT_N;
    for (int j = t; j < FFT_N; j += 256) {
        int a = swz(j);
        out1[j] = __float2bfloat16(bre[a]);
        out2[j] = __float2bfloat16(bim[a]);
    }
}

// ---------------- bf16 MFMA GEMM (unchanged from R9/R10) ----------------
__device__ __forceinline__ void stage_tile(const __hip_bfloat16* __restrict__ X,
                                           const __hip_bfloat16* __restrict__ W,
                                           __hip_bfloat16* __restrict__ buf,
                                           int m0, int n0, int tt, int wv, int ln) {
    const int k0n = tt * 64;
    __hip_bfloat16* bufB = buf + 8192;
    #pragma unroll
    for (int kk = 0; kk < 2; ++kk) {
        const int s = kk * 512 + wv * 64 + ln;
        const int row = s >> 3;
        const int cc = (s & 7) ^ (row & 7);
        const __hip_bfloat16* g = X + (size_t)(m0 + row) * IN_F + k0n + cc * 8;
        __builtin_amdgcn_global_load_lds(
            (const __attribute__((address_space(1))) void*)g,
            (__attribute__((address_space(3))) void*)(buf + (size_t)(kk * 512 + wv * 64) * 8),
            16, 0, 0);
    }
    #pragma unroll
    for (int u = 0; u < 2; ++u)
        #pragma unroll
        for (int kk = 0; kk < 2; ++kk) {
            const int s = kk * 512 + wv * 64 + ln;
            const int row = u * 128 + (s >> 3);
            const int cc = (s & 7) ^ (row & 7);
            const __hip_bfloat16* g = W + (size_t)(n0 + row) * IN_F + k0n + cc * 8;
            __builtin_amdgcn_global_load_lds(
                (const __attribute__((address_space(1))) void*)g,
                (__attribute__((address_space(3))) void*)(bufB + (size_t)(u * 1024 + kk * 512 + wv * 64) * 8),
                16, 0, 0);
        }
}

__global__ void __launch_bounds__(512, 2) gemm_kernel(const __hip_bfloat16* __restrict__ X,
                                                      const __hip_bfloat16* __restrict__ W,
                                                      const float* __restrict__ bias,
                                                      float* __restrict__ out) {
    __shared__ __align__(16) __hip_bfloat16 smem[3 * 24576];   // 144 KB
    const int tid = threadIdx.x;
    const int wv = tid >> 6;        // wave 0..7
    const int ln = tid & 63;
    const int m0 = blockIdx.y * 128;
    const int n0 = blockIdx.x * 256;
    const int wm = wv >> 2, wn = wv & 3;
    const int r16 = ln & 15, kg = ln >> 4;
    const int x7 = ln & 7;

    f32x4 acc[4][4];
    #pragma unroll
    for (int i = 0; i < 4; ++i)
        #pragma unroll
        for (int j = 0; j < 4; ++j) acc[i][j] = (f32x4){0.f, 0.f, 0.f, 0.f};

    stage_tile(X, W, smem, m0, n0, 0, wv, ln);
    stage_tile(X, W, smem + 24576, m0, n0, 1, wv, ln);
    asm volatile("s_waitcnt vmcnt(6)" ::: "memory");   // tile 0 landed
    __builtin_amdgcn_s_barrier();

    for (int t = 0; t < 64; ++t) {
        const __hip_bfloat16* Ab = smem + (t % 3) * 24576;
        const __hip_bfloat16* Bb = Ab + 8192;

        // phase A: k-half-0 fragment reads only + prefetch issue for tile t+2
        bf16x8 a0[4], b0[4];
        #pragma unroll
        for (int i = 0; i < 4; ++i) {
            const int R = wm * 64 + i * 16 + r16;
            a0[i] = *reinterpret_cast<const bf16x8*>(Ab + R * 64 + ((kg ^ x7) << 3));
        }
        #pragma unroll
        for (int j = 0; j < 4; ++j) {
            const int R = wn * 64 + j * 16 + r16;
            b0[j] = *reinterpret_cast<const bf16x8*>(Bb + R * 64 + ((kg ^ x7) << 3));
        }
        if (t < 62)
            stage_tile(X, W, smem + ((t + 2) % 3) * 24576, m0, n0, t + 2, wv, ln);

        __builtin_amdgcn_s_barrier();                          // BAR(A)
        asm volatile("s_waitcnt lgkmcnt(0)" ::: "memory");
        __builtin_amdgcn_sched_barrier(0);
        __builtin_amdgcn_s_setprio(1);
        #pragma unroll
        for (int i = 0; i < 2; ++i)
            #pragma unroll
            for (int j = 0; j < 4; ++j)
                acc[i][j] = __builtin_amdgcn_mfma_f32_16x16x32_bf16(a0[i], b0[j], acc[i][j], 0, 0, 0);
        // issue k-half-1 reads; they interleave with the remaining 8 MFMAs
        bf16x8 a1[4], b1[4];
        #pragma unroll
        for (int i = 0; i < 4; ++i) {
            const int R = wm * 64 + i * 16 + r16;
            a1[i] = *reinterpret_cast<const bf16x8*>(Ab + R * 64 + (((4 | kg) ^ x7) << 3));
        }
        #pragma unroll
        for (int j = 0; j < 4; ++j) {
            const int R = wn * 64 + j * 16 + r16;
            b1[j] = *reinterpret_cast<const bf16x8*>(Bb + R * 64 + (((4 | kg) ^ x7) << 3));
        }
        #pragma unroll
        for (int i = 2; i < 4; ++i)
            #pragma unroll
            for (int j = 0; j < 4; ++j)
                acc[i][j] = __builtin_amdgcn_mfma_f32_16x16x32_bf16(a0[i], b0[j], acc[i][j], 0, 0, 0);
        __builtin_amdgcn_s_setprio(0);

        if (t < 62) {
            asm volatile("s_waitcnt vmcnt(6)" ::: "memory");
        } else if (t == 62) {
            asm volatile("s_waitcnt vmcnt(0)" ::: "memory");
        }
        __builtin_amdgcn_s_barrier();                          // BAR(B)
        asm volatile("s_waitcnt lgkmcnt(0)" ::: "memory");     // a1/b1 landed
        __builtin_amdgcn_sched_barrier(0);

        __builtin_amdgcn_s_setprio(1);
        #pragma unroll
        for (int i = 0; i < 4; ++i)
            #pragma unroll
            for (int j = 0; j < 4; ++j)
                acc[i][j] = __builtin_amdgcn_mfma_f32_16x16x32_bf16(a1[i], b1[j], acc[i][j], 0, 0, 0);
        __builtin_amdgcn_s_setprio(0);
    }

    // epilogue: D[m][n], n = lane&15, m = (lane>>4)*4 + e
    #pragma unroll
    for (int i = 0; i < 4; ++i)
        #pragma unroll
        for (int j = 0; j < 4; ++j) {
            const int n = n0 + wn * 64 + j * 16 + r16;
            const float bs = bias[n];
            #pragma unroll
            for (int e = 0; e < 4; ++e) {
                const int m = m0 + wm * 64 + i * 16 + kg * 4 + e;
                out[(size_t)m * OUT_F + n] = acc[i][j][e] + bs;
            }
        }
}

extern "C" void kernel_launch(void* const* d_in, const int* in_sizes, int n_in,
                              void* d_out, int out_size, void* d_ws, size_t ws_size,
                              hipStream_t stream) {
    const float* x    = (const float*)d_in[0];
    const float* sre  = (const float*)d_in[1];
    const float* sim  = (const float*)d_in[2];
    const int*   sidx = (const int*)d_in[3];
    const float* bias = (const float*)d_in[4];
    const int nnz = in_sizes[1];
    float* out = (float*)d_out;

    char* ws = (char*)d_ws;
    // A (tiled bf16-packed intermediate, 512 panels x 2049 x 8 u32 = 33.6 MB) @ 0
    unsigned* A = (unsigned*)ws;
    // combined 16-B bucket entries @ 128 MiB (67.1 MB); dead before pass2 writes Wb
    uint4* bkt = (uint4*)(ws + 134217728);
    __hip_bfloat16* Wb = (__hip_bfloat16*)(ws + 134217728);               // 33.5 MB (pass2 out)
    __hip_bfloat16* Xb = (__hip_bfloat16*)(ws + 67108864);                // 16.8 MB
    unsigned* pos = (unsigned*)(ws + 100663296);                          // 16 KB

    hipMemsetAsync(pos, 0, 4096 * sizeof(unsigned), stream);

    const int sb = (nnz + 255) / 256;
    bucket_scatter_kernel<<<sb, 256, 0, stream>>>(sidx, sre, sim, pos, bkt, nnz);

    // pass 1: Hermitian-symmetrized scatter + IFFT over u; columns 0..2048 only
    ifft_pass1_kernel<<<HCOLS, 256, 0, stream>>>(pos, bkt, A);
    // pass 2 (+ fused x-cast): c2r IFFT over v, two rows per block -> bf16 weight
    ifft_pass2_kernel<<<2560, 256, 0, stream>>>(A, Wb, (const float4*)x, (ushort4*)Xb);

    gemm_kernel<<<dim3(OUT_F / 256, MROWS / 128), 512, 0, stream>>>(Xb, Wb, bias, out);
}